// Round 7
// baseline (430.459 us; speedup 1.0000x reference)
//
#include <hip/hip_runtime.h>
#include <hip/hip_bf16.h>

// Shapes
#define B_   32
#define L_   2048
#define D_   128
#define NL_  3
#define KVB  64
#define NKT  (L_ / KVB)         // 32

typedef __attribute__((ext_vector_type(8))) short short8;
typedef __attribute__((ext_vector_type(4))) float f32x4;
typedef __attribute__((ext_vector_type(16))) float f32x16;

__device__ __forceinline__ short f2bf(float f) {
    unsigned u = __builtin_bit_cast(unsigned, f);
    u += 0x7fffu + ((u >> 16) & 1u);          // RNE
    return (short)(u >> 16);
}
// pack two floats -> bf16 pair in one u32 (low = a, high = b), RNE
__device__ __forceinline__ unsigned pk2(float a, float b) {
    unsigned ua = __builtin_bit_cast(unsigned, a);
    ua += 0x7fffu + ((ua >> 16) & 1u);
    unsigned ub = __builtin_bit_cast(unsigned, b);
    ub += 0x7fffu + ((ub >> 16) & 1u);
    return (ua >> 16) | (ub & 0xffff0000u);
}
// swap halves across lane<32 / lane>=32 (m214 T12 pattern)
__device__ __forceinline__ void plswap(unsigned& a, unsigned& b) {
    asm volatile("v_permlane32_swap_b32 %0, %1" : "+v"(a), "+v"(b));
}

// async global -> LDS, 16 bytes per lane (dest must be linear: base + lane*16)
__device__ __forceinline__ void gll16(const void* g, void* l) {
    __builtin_amdgcn_global_load_lds(
        (__attribute__((address_space(1))) void*)(g),
        (__attribute__((address_space(3))) void*)(l), 16, 0, 0);
}

// ---------------------------------------------------------------- form x
__global__ __launch_bounds__(256) void k_form_x(const float* __restrict__ g,
                                                const float* __restrict__ emb,
                                                short* __restrict__ X) {
    int tid = blockIdx.x * 256 + threadIdx.x;   // one thread = 8 elements
    int bl  = tid >> 4;
    int d8  = (tid & 15) << 3;
    int l   = bl & (L_ - 1);
    float gv = g[bl];
    const float4* e = reinterpret_cast<const float4*>(emb + (size_t)l * D_ + d8);
    float4 a = e[0], b = e[1];
    short8 r;
    r[0]=f2bf(a.x*gv); r[1]=f2bf(a.y*gv); r[2]=f2bf(a.z*gv); r[3]=f2bf(a.w*gv);
    r[4]=f2bf(b.x*gv); r[5]=f2bf(b.y*gv); r[6]=f2bf(b.z*gv); r[7]=f2bf(b.w*gv);
    *reinterpret_cast<short8*>(X + (size_t)tid * 8) = r;
}

// ---------------------------------------------------------------- weight convert
// fp32 W -> bf16, stored PRE-SWIZZLED so k_qkv can gll16 it linearly.
__global__ __launch_bounds__(256) void k_convw(const float* __restrict__ qw,
                                               const float* __restrict__ kw,
                                               const float* __restrict__ vw,
                                               short* __restrict__ Wbf) {
    const float* src = (blockIdx.y == 0) ? qw : (blockIdx.y == 1) ? kw : vw;
    int tid = blockIdx.x * 256 + threadIdx.x;   // 0..6143
    int layer = tid >> 11;
    int i = tid & 2047;
    int Lb = i * 16;
    int row = Lb >> 8, c = (Lb & 255) ^ ((row & 7) << 4);
    const float4* p = reinterpret_cast<const float4*>(src + (size_t)layer * 16384 + row * 128 + (c >> 1));
    float4 a = p[0], b = p[1];
    short8 s;
    s[0]=f2bf(a.x); s[1]=f2bf(a.y); s[2]=f2bf(a.z); s[3]=f2bf(a.w);
    s[4]=f2bf(b.x); s[5]=f2bf(b.y); s[6]=f2bf(b.z); s[7]=f2bf(b.w);
    size_t off = ((size_t)layer * 3 + blockIdx.y) * 16384;
    *reinterpret_cast<short8*>(Wbf + off + (size_t)i * 8) = s;
}

// ---------------------------------------------------------------- QKV GEMM
__global__ __launch_bounds__(256, 2) void k_qkv(const short* __restrict__ X,
    const short* __restrict__ Wl,
    const float* __restrict__ bq, const float* __restrict__ bk, const float* __restrict__ bv,
    short* __restrict__ Qo, short* __restrict__ Ko, short* __restrict__ Vto) {
    __shared__ short xs[128 * 128];
    __shared__ short wsh[128 * 128];
    const int t = threadIdx.x;
    const float* bias = (blockIdx.y == 0) ? bq : (blockIdx.y == 1) ? bk : bv;
    const short* Wg = Wl + (size_t)blockIdx.y * 16384;
    const size_t rowbase = (size_t)blockIdx.x * 128;

    const char* Xg = reinterpret_cast<const char*>(X) + rowbase * 256;
#pragma unroll
    for (int p = 0; p < 8; p++) {
        int Lb = (p * 256 + t) * 16;
        int row = Lb >> 8, c = Lb & 255;
        gll16(Xg + (size_t)row * 256 + (c ^ ((row & 7) << 4)),
              reinterpret_cast<char*>(xs) + Lb);
    }
#pragma unroll
    for (int p = 0; p < 8; p++) {
        int Lb = (p * 256 + t) * 16;
        gll16(reinterpret_cast<const char*>(Wg) + Lb,
              reinterpret_cast<char*>(wsh) + Lb);
    }
    __syncthreads();

    const int wave = t >> 6, lane = t & 63, g = lane >> 4, ln = lane & 15;
    f32x4 acc[2][8];
#pragma unroll
    for (int mi = 0; mi < 2; mi++)
#pragma unroll
        for (int ni = 0; ni < 8; ni++) acc[mi][ni] = f32x4{0.f, 0.f, 0.f, 0.f};

    if (blockIdx.y < 2) {
#pragma unroll
        for (int kk = 0; kk < 4; kk++) {
            short8 aW[2];
#pragma unroll
            for (int mi = 0; mi < 2; mi++) {
                int row = wave * 32 + mi * 16 + ln;
                int byte = (row * 256 + kk * 64 + g * 16) ^ ((row & 7) << 4);
                aW[mi] = *reinterpret_cast<const short8*>(reinterpret_cast<const char*>(wsh) + byte);
            }
#pragma unroll
            for (int ni = 0; ni < 8; ni++) {
                int row = ni * 16 + ln;
                int byte = (row * 256 + kk * 64 + g * 16) ^ ((row & 7) << 4);
                short8 bX = *reinterpret_cast<const short8*>(reinterpret_cast<const char*>(xs) + byte);
                acc[0][ni] = __builtin_amdgcn_mfma_f32_16x16x32_bf16(aW[0], bX, acc[0][ni], 0, 0, 0);
                acc[1][ni] = __builtin_amdgcn_mfma_f32_16x16x32_bf16(aW[1], bX, acc[1][ni], 0, 0, 0);
            }
        }
        short* out = (blockIdx.y == 0) ? Qo : Ko;
#pragma unroll
        for (int mi = 0; mi < 2; mi++) {
            int e0 = wave * 32 + mi * 16 + g * 4;
            float4 b4 = *reinterpret_cast<const float4*>(bias + e0);
#pragma unroll
            for (int ni = 0; ni < 8; ni++) {
                unsigned lo = (unsigned short)f2bf(acc[mi][ni][0] + b4.x)
                            | ((unsigned)(unsigned short)f2bf(acc[mi][ni][1] + b4.y) << 16);
                unsigned hi2 = (unsigned short)f2bf(acc[mi][ni][2] + b4.z)
                            | ((unsigned)(unsigned short)f2bf(acc[mi][ni][3] + b4.w) << 16);
                int2 pk; pk.x = (int)lo; pk.y = (int)hi2;
                *reinterpret_cast<int2*>(out + (rowbase + ni * 16 + ln) * D_ + e0) = pk;
            }
        }
    } else {
#pragma unroll
        for (int kk = 0; kk < 4; kk++) {
            short8 aX[2];
#pragma unroll
            for (int mi = 0; mi < 2; mi++) {
                int row = wave * 32 + mi * 16 + ln;
                int byte = (row * 256 + kk * 64 + g * 16) ^ ((row & 7) << 4);
                aX[mi] = *reinterpret_cast<const short8*>(reinterpret_cast<const char*>(xs) + byte);
            }
#pragma unroll
            for (int ni = 0; ni < 8; ni++) {
                int row = ni * 16 + ln;
                int byte = (row * 256 + kk * 64 + g * 16) ^ ((row & 7) << 4);
                short8 bW = *reinterpret_cast<const short8*>(reinterpret_cast<const char*>(wsh) + byte);
                acc[0][ni] = __builtin_amdgcn_mfma_f32_16x16x32_bf16(aX[0], bW, acc[0][ni], 0, 0, 0);
                acc[1][ni] = __builtin_amdgcn_mfma_f32_16x16x32_bf16(aX[1], bW, acc[1][ni], 0, 0, 0);
            }
        }
        int bb2 = (int)(rowbase >> 11);
        int l0  = (int)(rowbase & (L_ - 1));
#pragma unroll
        for (int ni = 0; ni < 8; ni++) {
            int col = ni * 16 + ln;
            float bvv = bias[col];
#pragma unroll
            for (int mi = 0; mi < 2; mi++) {
                unsigned lo = (unsigned short)f2bf(acc[mi][ni][0] + bvv)
                            | ((unsigned)(unsigned short)f2bf(acc[mi][ni][1] + bvv) << 16);
                unsigned hi2 = (unsigned short)f2bf(acc[mi][ni][2] + bvv)
                            | ((unsigned)(unsigned short)f2bf(acc[mi][ni][3] + bvv) << 16);
                int l = l0 + wave * 32 + mi * 16 + g * 4;
                int2 pk; pk.x = (int)lo; pk.y = (int)hi2;
                *reinterpret_cast<int2*>(Vto + ((size_t)bb2 * D_ + col) * L_ + l) = pk;
            }
        }
    }
}

// ---------------------------------------------------------------- flash attention
// 32x32x16 MFMA; swapped QK^T; in-register P via permlane32_swap; KVBLK=64.
// FRAGMENT-ORDERED LDS: K as [dst:8][half:2][lane:64]x16B, Vt as [k16:4][d2:4][lane:64]x16B.
// Every ds_read_b128 is base + lane*16 -> consecutive banks -> zero conflicts.
// Per-lane global src addresses absorb the permutation (gll16 dest stays linear).
__global__ __launch_bounds__(256, 2) void k_attn(const short* __restrict__ Q,
                                                 const short* __restrict__ K,
                                                 const short* __restrict__ Vt,
                                                 short* __restrict__ Xo,
                                                 const float* __restrict__ rw,
                                                 const float* __restrict__ rb,
                                                 float* __restrict__ out,
                                                 int fuse) {
    __shared__ short Ks[2][KVB * 128];    // 2 x 16 KB, fragment order
    __shared__ short Vts[2][128 * KVB];   // 2 x 16 KB, fragment order
    const int t = threadIdx.x, w = t >> 6, lane = t & 63;
    const int hi = lane >> 5, c5 = lane & 31;
    // XCD-aware remap: each XCD owns 4 batches x 16 q-tiles (K/V L2-resident)
    int flat = blockIdx.x;
    int xcd = flat & 7, idx = flat >> 3;
    int b = xcd * 4 + (idx >> 4), qt = idx & 15;
    const size_t qbase = (size_t)b * L_ + qt * 128;

    // Q fragments -> registers: B-operand, lane holds Q[q=c5][d = dst*16 + hi*8 + j]
    short8 qf[8];
    {
        const short* qp = Q + (qbase + w * 32 + c5) * D_;
#pragma unroll
        for (int dst = 0; dst < 8; dst++)
            qf[dst] = *reinterpret_cast<const short8*>(qp + dst * 16 + hi * 8);
    }

    const char* Kg = reinterpret_cast<const char*>(K + (size_t)b * L_ * D_);
    const char* Vg = reinterpret_cast<const char*>(Vt + (size_t)b * D_ * L_);

    // stage KV tile kt in fragment order: LDS dest linear, global src per-lane computed.
    // K LDS off = dst*2048 + half*1024 + l*16  <- K[half*32 + (l&31)][dst*16 + (l>>5)*8 ..]
    // Vt LDS off = k16*4096 + d2*1024 + l*16   <- Vt[d2*32 + (l&31)][k16*16 + (l>>5)*8 ..]
    auto stage = [&](int kt, int buf) {
#pragma unroll
        for (int p = 0; p < 4; p++) {
            int Lb = (p * 256 + t) * 16;
            int dst = Lb >> 11, half = (Lb >> 10) & 1, l = (Lb >> 4) & 63;
            int row = half * 32 + (l & 31);
            int col = dst * 32 + (l >> 5) * 16;
            gll16(Kg + (size_t)kt * (KVB * 256) + row * 256 + col,
                  reinterpret_cast<char*>(Ks[buf]) + Lb);
        }
#pragma unroll
        for (int p = 0; p < 4; p++) {
            int Lb = (p * 256 + t) * 16;
            int k16 = Lb >> 12, d2 = (Lb >> 10) & 3, l = (Lb >> 4) & 63;
            int drow = d2 * 32 + (l & 31);
            int col = k16 * 32 + (l >> 5) * 16;
            gll16(Vg + (size_t)drow * (L_ * 2) + kt * 128 + col,
                  reinterpret_cast<char*>(Vts[buf]) + Lb);
        }
    };

    stage(0, 0);
    stage(1, 1);

    f32x16 o[4];
#pragma unroll
    for (int d2 = 0; d2 < 4; d2++)
#pragma unroll
        for (int r = 0; r < 16; r++) o[d2][r] = 0.f;
    float lsum = 0.f;

    int cur = 0;
    for (int kt = 0; kt < NKT; kt++) {
        if (kt < NKT - 1) asm volatile("s_waitcnt vmcnt(8)" ::: "memory");
        else              asm volatile("s_waitcnt vmcnt(0)" ::: "memory");
        __builtin_amdgcn_sched_barrier(0);
        __builtin_amdgcn_s_barrier();           // tile kt fully in LDS

        const char* Kb8 = reinterpret_cast<const char*>(Ks[cur]) + lane * 16;
        const char* Vb8 = reinterpret_cast<const char*>(Vts[cur]) + lane * 16;

        // S^T = K.Q^T : two 32x32 k-tiles, 8 d-steps each
        f32x16 s0, s1;
#pragma unroll
        for (int r = 0; r < 16; r++) { s0[r] = 0.f; s1[r] = 0.f; }
        __builtin_amdgcn_s_setprio(1);
#pragma unroll
        for (int dst = 0; dst < 8; dst++) {
            short8 kf0 = *reinterpret_cast<const short8*>(Kb8 + dst * 2048);
            short8 kf1 = *reinterpret_cast<const short8*>(Kb8 + dst * 2048 + 1024);
            s0 = __builtin_amdgcn_mfma_f32_32x32x16_bf16(kf0, qf[dst], s0, 0, 0, 0);
            s1 = __builtin_amdgcn_mfma_f32_32x32x16_bf16(kf1, qf[dst], s1, 0, 0, 0);
        }
        __builtin_amdgcn_s_setprio(0);

        // exp (unshifted) + in-register P-frag assembly via permlane32_swap
        float e0[16], e1[16];
#pragma unroll
        for (int r = 0; r < 16; r++) { e0[r] = __expf(s0[r]); e1[r] = __expf(s1[r]); }
#pragma unroll
        for (int r = 0; r < 16; r++) lsum += e0[r] + e1[r];

        short8 pa[4];
#pragma unroll
        for (int kt16 = 0; kt16 < 4; kt16++) {
            const float* e = (kt16 < 2) ? e0 : e1;
            int rb2 = (kt16 & 1) * 8;
            unsigned w01 = pk2(e[rb2 + 0], e[rb2 + 1]);
            unsigned w23 = pk2(e[rb2 + 2], e[rb2 + 3]);
            unsigned w45 = pk2(e[rb2 + 4], e[rb2 + 5]);
            unsigned w67 = pk2(e[rb2 + 6], e[rb2 + 7]);
            plswap(w01, w45);
            plswap(w23, w67);
            uint4 fr; fr.x = w01; fr.y = w23; fr.z = w45; fr.w = w67;
            pa[kt16] = __builtin_bit_cast(short8, fr);
        }

        // O += P.V : 4 k16-slices x 4 d-blocks
        __builtin_amdgcn_s_setprio(1);
#pragma unroll
        for (int kt16 = 0; kt16 < 4; kt16++) {
#pragma unroll
            for (int d2 = 0; d2 < 4; d2++) {
                short8 vf = *reinterpret_cast<const short8*>(Vb8 + kt16 * 4096 + d2 * 1024);
                o[d2] = __builtin_amdgcn_mfma_f32_32x32x16_bf16(pa[kt16], vf, o[d2], 0, 0, 0);
            }
        }
        __builtin_amdgcn_s_setprio(0);

        __builtin_amdgcn_sched_barrier(0);
        __builtin_amdgcn_s_barrier();           // all waves done reading buf[cur]
        if (kt + 2 < NKT) stage(kt + 2, cur);   // overwrite now-free buffer
        cur ^= 1;
    }

    // denominators: lane holds partial for q=c5 over its hi-half k-set
    lsum += __shfl_xor(lsum, 32, 64);           // full sum for q=c5 in all lanes

    if (!fuse) {
#pragma unroll
        for (int reg = 0; reg < 16; reg++) {
            int crow = (reg & 3) + 8 * (reg >> 2) + 4 * hi;   // q-local
            float inv = 1.0f / __shfl(lsum, crow, 64);
            size_t rowg = qbase + w * 32 + crow;
#pragma unroll
            for (int d2 = 0; d2 < 4; d2++)
                Xo[rowg * D_ + d2 * 32 + c5] = f2bf(o[d2][reg] * inv);
        }
    } else {
        float part = 0.f;
#pragma unroll
        for (int reg = 0; reg < 16; reg++) {
            int crow = (reg & 3) + 8 * (reg >> 2) + 4 * hi;
            float inv = 1.0f / __shfl(lsum, crow, 64);
            size_t rowg = (size_t)(qt * 128 + w * 32 + crow) * D_;
#pragma unroll
            for (int d2 = 0; d2 < 4; d2++)
                part += (o[d2][reg] * inv) * rw[rowg + d2 * 32 + c5];
        }
#pragma unroll
        for (int off = 32; off > 0; off >>= 1) part += __shfl_xor(part, off, 64);
        if (lane == 0) atomicAdd(out + b, part);
        if (qt == 0 && t == 0) atomicAdd(out + b, rb[0]);
    }
}

// ---------------------------------------------------------------- launch
extern "C" void kernel_launch(void* const* d_in, const int* in_sizes, int n_in,
                              void* d_out, int out_size, void* d_ws, size_t ws_size,
                              hipStream_t stream) {
    const float* genotypes = (const float*)d_in[0];
    const float* emb       = (const float*)d_in[1];
    const float* qw        = (const float*)d_in[2];
    const float* qb        = (const float*)d_in[3];
    const float* kw        = (const float*)d_in[4];
    const float* kb        = (const float*)d_in[5];
    const float* vw        = (const float*)d_in[6];
    const float* vb        = (const float*)d_in[7];
    const float* rw        = (const float*)d_in[8];
    const float* rb        = (const float*)d_in[9];
    float* out = (float*)d_out;

    const size_t NBL = (size_t)B_ * L_;        // 65536
    short* X   = (short*)d_ws;
    short* Qb  = X  + NBL * D_;
    short* Kb  = Qb + NBL * D_;
    short* Vtb = Kb + NBL * D_;
    short* Wbf = Vtb + NBL * D_;               // 3 layers x 3 mats x 16384 bf16 (pre-swizzled)

    hipMemsetAsync(out, 0, out_size * sizeof(float), stream);
    k_form_x<<<dim3((NBL * D_ / 8) / 256), 256, 0, stream>>>(genotypes, emb, X);
    k_convw<<<dim3(24, 3), 256, 0, stream>>>(qw, kw, vw, Wbf);
    for (int layer = 0; layer < NL_; layer++) {
        int boff = layer * D_;
        k_qkv<<<dim3(NBL / 128, 3), 256, 0, stream>>>(X, Wbf + (size_t)layer * 3 * 16384,
                                                      qb + boff, kb + boff, vb + boff,
                                                      Qb, Kb, Vtb);
        k_attn<<<dim3(512), 256, 0, stream>>>(Qb, Kb, Vtb, X, rw, rb, out,
                                              layer == NL_ - 1 ? 1 : 0);
    }
}

// Round 8
// 363.364 us; speedup vs baseline: 1.1847x; 1.1847x over previous
//
#include <hip/hip_runtime.h>
#include <hip/hip_bf16.h>

// Shapes
#define B_   32
#define L_   2048
#define D_   128
#define NL_  3
#define KVB  64
#define NKT  (L_ / KVB)         // 32

typedef __attribute__((ext_vector_type(8))) short short8;
typedef __attribute__((ext_vector_type(4))) float f32x4;
typedef __attribute__((ext_vector_type(16))) float f32x16;

__device__ __forceinline__ short f2bf(float f) {
    unsigned u = __builtin_bit_cast(unsigned, f);
    u += 0x7fffu + ((u >> 16) & 1u);          // RNE
    return (short)(u >> 16);
}
// pack two floats -> bf16 pair in one u32 (low = a, high = b), RNE
__device__ __forceinline__ unsigned pk2(float a, float b) {
    unsigned ua = __builtin_bit_cast(unsigned, a);
    ua += 0x7fffu + ((ua >> 16) & 1u);
    unsigned ub = __builtin_bit_cast(unsigned, b);
    ub += 0x7fffu + ((ub >> 16) & 1u);
    return (ua >> 16) | (ub & 0xffff0000u);
}
// swap halves across lane<32 / lane>=32 (m214 T12 pattern)
__device__ __forceinline__ void plswap(unsigned& a, unsigned& b) {
    asm volatile("v_permlane32_swap_b32 %0, %1" : "+v"(a), "+v"(b));
}

// async global -> LDS, 16 bytes per lane (dest must be linear: base + lane*16)
__device__ __forceinline__ void gll16(const void* g, void* l) {
    __builtin_amdgcn_global_load_lds(
        (__attribute__((address_space(1))) void*)(g),
        (__attribute__((address_space(3))) void*)(l), 16, 0, 0);
}

// Fragment-order global layouts (16B granule per lane):
//  Q/K: addr = b*512K + blk32*8K + dst*1K + lane*16
//       content: Row[blk32*32 + (lane&31)], d-elems dst*16 + (lane>>5)*8 .. +8
//  Vt:  addr = b*512K + kt*16K + k16*4K + d2*1K + lane*16
//       content: V^T[d = d2*32 + (lane&31)][l = kt*64 + k16*16 + (lane>>5)*8 .. +8]

// ---------------------------------------------------------------- form x
__global__ __launch_bounds__(256) void k_form_x(const float* __restrict__ g,
                                                const float* __restrict__ emb,
                                                short* __restrict__ X) {
    int tid = blockIdx.x * 256 + threadIdx.x;   // one thread = 8 elements
    int bl  = tid >> 4;
    int d8  = (tid & 15) << 3;
    int l   = bl & (L_ - 1);
    float gv = g[bl];
    const float4* e = reinterpret_cast<const float4*>(emb + (size_t)l * D_ + d8);
    float4 a = e[0], b = e[1];
    short8 r;
    r[0]=f2bf(a.x*gv); r[1]=f2bf(a.y*gv); r[2]=f2bf(a.z*gv); r[3]=f2bf(a.w*gv);
    r[4]=f2bf(b.x*gv); r[5]=f2bf(b.y*gv); r[6]=f2bf(b.z*gv); r[7]=f2bf(b.w*gv);
    *reinterpret_cast<short8*>(X + (size_t)tid * 8) = r;
}

// ---------------------------------------------------------------- weight convert
// fp32 W -> bf16, stored PRE-SWIZZLED so k_qkv can gll16 it linearly.
__global__ __launch_bounds__(256) void k_convw(const float* __restrict__ qw,
                                               const float* __restrict__ kw,
                                               const float* __restrict__ vw,
                                               short* __restrict__ Wbf) {
    const float* src = (blockIdx.y == 0) ? qw : (blockIdx.y == 1) ? kw : vw;
    int tid = blockIdx.x * 256 + threadIdx.x;   // 0..6143
    int layer = tid >> 11;
    int i = tid & 2047;
    int Lb = i * 16;
    int row = Lb >> 8, c = (Lb & 255) ^ ((row & 7) << 4);
    const float4* p = reinterpret_cast<const float4*>(src + (size_t)layer * 16384 + row * 128 + (c >> 1));
    float4 a = p[0], b = p[1];
    short8 s;
    s[0]=f2bf(a.x); s[1]=f2bf(a.y); s[2]=f2bf(a.z); s[3]=f2bf(a.w);
    s[4]=f2bf(b.x); s[5]=f2bf(b.y); s[6]=f2bf(b.z); s[7]=f2bf(b.w);
    size_t off = ((size_t)layer * 3 + blockIdx.y) * 16384;
    *reinterpret_cast<short8*>(Wbf + off + (size_t)i * 8) = s;
}

// ---------------------------------------------------------------- QKV GEMM
// Flat 1536-block grid, XCD-grouped: each XCD owns 64 row-blocks x 3 mats.
// Outputs written in FRAGMENT ORDER (see layouts above).
__global__ __launch_bounds__(256, 2) void k_qkv(const short* __restrict__ X,
    const short* __restrict__ Wl,
    const float* __restrict__ bq, const float* __restrict__ bk, const float* __restrict__ bv,
    short* __restrict__ Qf, short* __restrict__ Kf, short* __restrict__ Vf) {
    __shared__ short xs[128 * 128];
    __shared__ short wsh[128 * 128];
    const int t = threadIdx.x;
    int flat = blockIdx.x, xcd = flat & 7, idx = flat >> 3;
    int mat = idx >> 6, rblk = xcd * 64 + (idx & 63);
    const float* bias = (mat == 0) ? bq : (mat == 1) ? bk : bv;
    const short* Wg = Wl + (size_t)mat * 16384;
    const size_t rowbase = (size_t)rblk * 128;

    const char* Xg = reinterpret_cast<const char*>(X) + rowbase * 256;
#pragma unroll
    for (int p = 0; p < 8; p++) {
        int Lb = (p * 256 + t) * 16;
        int row = Lb >> 8, c = Lb & 255;
        gll16(Xg + (size_t)row * 256 + (c ^ ((row & 7) << 4)),
              reinterpret_cast<char*>(xs) + Lb);
    }
#pragma unroll
    for (int p = 0; p < 8; p++) {
        int Lb = (p * 256 + t) * 16;
        gll16(reinterpret_cast<const char*>(Wg) + Lb,
              reinterpret_cast<char*>(wsh) + Lb);
    }
    __syncthreads();

    const int wave = t >> 6, lane = t & 63, g = lane >> 4, ln = lane & 15;
    const int bb2 = (int)(rowbase >> 11);      // batch
    const int l0  = (int)(rowbase & (L_ - 1)); // row within batch
    f32x4 acc[2][8];
#pragma unroll
    for (int mi = 0; mi < 2; mi++)
#pragma unroll
        for (int ni = 0; ni < 8; ni++) acc[mi][ni] = f32x4{0.f, 0.f, 0.f, 0.f};

    if (mat < 2) {
        // A = W (rows e), B = X (rows l) -> C[e][l]
#pragma unroll
        for (int kk = 0; kk < 4; kk++) {
            short8 aW[2];
#pragma unroll
            for (int mi = 0; mi < 2; mi++) {
                int row = wave * 32 + mi * 16 + ln;
                int byte = (row * 256 + kk * 64 + g * 16) ^ ((row & 7) << 4);
                aW[mi] = *reinterpret_cast<const short8*>(reinterpret_cast<const char*>(wsh) + byte);
            }
#pragma unroll
            for (int ni = 0; ni < 8; ni++) {
                int row = ni * 16 + ln;
                int byte = (row * 256 + kk * 64 + g * 16) ^ ((row & 7) << 4);
                short8 bX = *reinterpret_cast<const short8*>(reinterpret_cast<const char*>(xs) + byte);
                acc[0][ni] = __builtin_amdgcn_mfma_f32_16x16x32_bf16(aW[0], bX, acc[0][ni], 0, 0, 0);
                acc[1][ni] = __builtin_amdgcn_mfma_f32_16x16x32_bf16(aW[1], bX, acc[1][ni], 0, 0, 0);
            }
        }
        // store in fragment order: granule(blk32, dst, lane'), half-granule by (g&1)
        char* oc = reinterpret_cast<char*>((mat == 0) ? Qf : Kf) + ((size_t)bb2 << 19);
        int lidx_hi = ((g >> 1) & 1) << 5;     // d-half within granule lane index
#pragma unroll
        for (int mi = 0; mi < 2; mi++) {
            int e0 = wave * 32 + mi * 16 + g * 4;
            int dst = wave * 2 + mi;
            float4 b4 = *reinterpret_cast<const float4*>(bias + e0);
#pragma unroll
            for (int ni = 0; ni < 8; ni++) {
                unsigned lo = (unsigned short)f2bf(acc[mi][ni][0] + b4.x)
                            | ((unsigned)(unsigned short)f2bf(acc[mi][ni][1] + b4.y) << 16);
                unsigned hi2 = (unsigned short)f2bf(acc[mi][ni][2] + b4.z)
                            | ((unsigned)(unsigned short)f2bf(acc[mi][ni][3] + b4.w) << 16);
                int blk32 = (l0 >> 5) + (ni >> 1);
                int l31 = ((ni & 1) << 4) + ln;
                size_t off = ((size_t)(blk32 * 8 + dst) << 10)
                           + ((lidx_hi + l31) << 4) + ((g & 1) << 3);
                int2 pk; pk.x = (int)lo; pk.y = (int)hi2;
                *reinterpret_cast<int2*>(oc + off) = pk;
            }
        }
    } else {
        // V: A = X (rows l), B = W (rows e) -> C[l][e]
#pragma unroll
        for (int kk = 0; kk < 4; kk++) {
            short8 aX[2];
#pragma unroll
            for (int mi = 0; mi < 2; mi++) {
                int row = wave * 32 + mi * 16 + ln;
                int byte = (row * 256 + kk * 64 + g * 16) ^ ((row & 7) << 4);
                aX[mi] = *reinterpret_cast<const short8*>(reinterpret_cast<const char*>(xs) + byte);
            }
#pragma unroll
            for (int ni = 0; ni < 8; ni++) {
                int row = ni * 16 + ln;
                int byte = (row * 256 + kk * 64 + g * 16) ^ ((row & 7) << 4);
                short8 bW = *reinterpret_cast<const short8*>(reinterpret_cast<const char*>(wsh) + byte);
                acc[0][ni] = __builtin_amdgcn_mfma_f32_16x16x32_bf16(aX[0], bW, acc[0][ni], 0, 0, 0);
                acc[1][ni] = __builtin_amdgcn_mfma_f32_16x16x32_bf16(aX[1], bW, acc[1][ni], 0, 0, 0);
            }
        }
        // store in fragment order: granule(kt, k16, d2, lane'), half-granule by (g&1)
        char* oc = reinterpret_cast<char*>(Vf) + ((size_t)bb2 << 19);
#pragma unroll
        for (int ni = 0; ni < 8; ni++) {
            int d = ni * 16 + ln;
            float bvv = bias[d];
            int d2 = d >> 5, d31 = d & 31;
#pragma unroll
            for (int mi = 0; mi < 2; mi++) {
                unsigned lo = (unsigned short)f2bf(acc[mi][ni][0] + bvv)
                            | ((unsigned)(unsigned short)f2bf(acc[mi][ni][1] + bvv) << 16);
                unsigned hi2 = (unsigned short)f2bf(acc[mi][ni][2] + bvv)
                            | ((unsigned)(unsigned short)f2bf(acc[mi][ni][3] + bvv) << 16);
                int lglob = l0 + wave * 32 + mi * 16 + g * 4;
                int kt = lglob >> 6, k16 = (lglob >> 4) & 3, lhi = (lglob >> 3) & 1;
                size_t off = ((size_t)kt << 14) + (k16 << 12) + (d2 << 10)
                           + ((lhi * 32 + d31) << 4) + ((g & 1) << 3);
                int2 pk; pk.x = (int)lo; pk.y = (int)hi2;
                *reinterpret_cast<int2*>(oc + off) = pk;
            }
        }
    }
}

// ---------------------------------------------------------------- flash attention
// 32x32x16 MFMA; swapped QK^T; in-register P via permlane32_swap; KVBLK=64.
// Q/K/Vt pre-laid-out in global FRAGMENT ORDER -> staging is contiguous gll16
// (coalesced) AND every ds_read_b128 is base + lane*16 (zero conflicts).
__global__ __launch_bounds__(256, 2) void k_attn(const short* __restrict__ Qf,
                                                 const short* __restrict__ Kf,
                                                 const short* __restrict__ Vf,
                                                 short* __restrict__ Xo,
                                                 const float* __restrict__ rw,
                                                 const float* __restrict__ rb,
                                                 float* __restrict__ out,
                                                 int fuse) {
    __shared__ short Ks[2][KVB * 128];    // 2 x 16 KB, fragment order
    __shared__ short Vts[2][128 * KVB];   // 2 x 16 KB, fragment order
    const int t = threadIdx.x, w = t >> 6, lane = t & 63;
    const int hi = lane >> 5, c5 = lane & 31;
    // XCD-aware remap: each XCD owns 4 batches x 16 q-tiles (K/V L2-resident)
    int flat = blockIdx.x;
    int xcd = flat & 7, idx = flat >> 3;
    int b = xcd * 4 + (idx >> 4), qt = idx & 15;
    const size_t qbase = (size_t)b * L_ + qt * 128;

    // Q fragments -> registers (contiguous 1KB per load: fragment-order global)
    const char* Qg = reinterpret_cast<const char*>(Qf) + ((size_t)b << 19);
    short8 qf[8];
#pragma unroll
    for (int dst = 0; dst < 8; dst++)
        qf[dst] = *reinterpret_cast<const short8*>(
            Qg + (((size_t)(qt * 4 + w) * 8 + dst) << 10) + lane * 16);

    const char* Kg = reinterpret_cast<const char*>(Kf) + ((size_t)b << 19);
    const char* Vg = reinterpret_cast<const char*>(Vf) + ((size_t)b << 19);

    // stage KV tile kt: pure linear copy (global fragment-order -> LDS)
    auto stage = [&](int kt, int buf) {
#pragma unroll
        for (int p = 0; p < 4; p++) {
            int Lb = (p * 256 + t) * 16;
            gll16(Kg + ((size_t)kt << 14) + Lb, reinterpret_cast<char*>(Ks[buf]) + Lb);
        }
#pragma unroll
        for (int p = 0; p < 4; p++) {
            int Lb = (p * 256 + t) * 16;
            gll16(Vg + ((size_t)kt << 14) + Lb, reinterpret_cast<char*>(Vts[buf]) + Lb);
        }
    };

    stage(0, 0);
    stage(1, 1);

    f32x16 o[4];
#pragma unroll
    for (int d2 = 0; d2 < 4; d2++)
#pragma unroll
        for (int r = 0; r < 16; r++) o[d2][r] = 0.f;
    float lsum = 0.f;

    int cur = 0;
    for (int kt = 0; kt < NKT; kt++) {
        if (kt < NKT - 1) asm volatile("s_waitcnt vmcnt(8)" ::: "memory");
        else              asm volatile("s_waitcnt vmcnt(0)" ::: "memory");
        __builtin_amdgcn_sched_barrier(0);
        __builtin_amdgcn_s_barrier();           // tile kt fully in LDS

        const char* Kb8 = reinterpret_cast<const char*>(Ks[cur]) + lane * 16;
        const char* Vb8 = reinterpret_cast<const char*>(Vts[cur]) + lane * 16;

        // S^T = K.Q^T : two 32x32 k-tiles, 8 d-steps each
        f32x16 s0, s1;
#pragma unroll
        for (int r = 0; r < 16; r++) { s0[r] = 0.f; s1[r] = 0.f; }
        __builtin_amdgcn_s_setprio(1);
#pragma unroll
        for (int dst = 0; dst < 8; dst++) {
            short8 kf0 = *reinterpret_cast<const short8*>(Kb8 + dst * 1024);
            short8 kf1 = *reinterpret_cast<const short8*>(Kb8 + 8192 + dst * 1024);
            s0 = __builtin_amdgcn_mfma_f32_32x32x16_bf16(kf0, qf[dst], s0, 0, 0, 0);
            s1 = __builtin_amdgcn_mfma_f32_32x32x16_bf16(kf1, qf[dst], s1, 0, 0, 0);
        }
        __builtin_amdgcn_s_setprio(0);

        // exp (unshifted) + in-register P-frag assembly via permlane32_swap
        float e0[16], e1[16];
#pragma unroll
        for (int r = 0; r < 16; r++) { e0[r] = __expf(s0[r]); e1[r] = __expf(s1[r]); }
#pragma unroll
        for (int r = 0; r < 16; r++) lsum += e0[r] + e1[r];

        short8 pa[4];
#pragma unroll
        for (int kt16 = 0; kt16 < 4; kt16++) {
            const float* e = (kt16 < 2) ? e0 : e1;
            int rb2 = (kt16 & 1) * 8;
            unsigned w01 = pk2(e[rb2 + 0], e[rb2 + 1]);
            unsigned w23 = pk2(e[rb2 + 2], e[rb2 + 3]);
            unsigned w45 = pk2(e[rb2 + 4], e[rb2 + 5]);
            unsigned w67 = pk2(e[rb2 + 6], e[rb2 + 7]);
            plswap(w01, w45);
            plswap(w23, w67);
            uint4 fr; fr.x = w01; fr.y = w23; fr.z = w45; fr.w = w67;
            pa[kt16] = __builtin_bit_cast(short8, fr);
        }

        // O += P.V : 4 k16-slices x 4 d-blocks
        __builtin_amdgcn_s_setprio(1);
#pragma unroll
        for (int kt16 = 0; kt16 < 4; kt16++) {
#pragma unroll
            for (int d2 = 0; d2 < 4; d2++) {
                short8 vf = *reinterpret_cast<const short8*>(Vb8 + kt16 * 4096 + d2 * 1024);
                o[d2] = __builtin_amdgcn_mfma_f32_32x32x16_bf16(pa[kt16], vf, o[d2], 0, 0, 0);
            }
        }
        __builtin_amdgcn_s_setprio(0);

        __builtin_amdgcn_sched_barrier(0);
        __builtin_amdgcn_s_barrier();           // all waves done reading buf[cur]
        if (kt + 2 < NKT) stage(kt + 2, cur);   // overwrite now-free buffer
        cur ^= 1;
    }

    // denominators: lane holds partial for q=c5 over its hi-half k-set
    lsum += __shfl_xor(lsum, 32, 64);           // full sum for q=c5 in all lanes

    if (!fuse) {
#pragma unroll
        for (int reg = 0; reg < 16; reg++) {
            int crow = (reg & 3) + 8 * (reg >> 2) + 4 * hi;   // q-local
            float inv = 1.0f / __shfl(lsum, crow, 64);
            size_t rowg = qbase + w * 32 + crow;
#pragma unroll
            for (int d2 = 0; d2 < 4; d2++)
                Xo[rowg * D_ + d2 * 32 + c5] = f2bf(o[d2][reg] * inv);
        }
    } else {
        float part = 0.f;
#pragma unroll
        for (int reg = 0; reg < 16; reg++) {
            int crow = (reg & 3) + 8 * (reg >> 2) + 4 * hi;
            float inv = 1.0f / __shfl(lsum, crow, 64);
            size_t rowg = (size_t)(qt * 128 + w * 32 + crow) * D_;
#pragma unroll
            for (int d2 = 0; d2 < 4; d2++)
                part += (o[d2][reg] * inv) * rw[rowg + d2 * 32 + c5];
        }
#pragma unroll
        for (int off = 32; off > 0; off >>= 1) part += __shfl_xor(part, off, 64);
        if (lane == 0) atomicAdd(out + b, part);
        if (qt == 0 && t == 0) atomicAdd(out + b, rb[0]);
    }
}

// ---------------------------------------------------------------- launch
extern "C" void kernel_launch(void* const* d_in, const int* in_sizes, int n_in,
                              void* d_out, int out_size, void* d_ws, size_t ws_size,
                              hipStream_t stream) {
    const float* genotypes = (const float*)d_in[0];
    const float* emb       = (const float*)d_in[1];
    const float* qw        = (const float*)d_in[2];
    const float* qb        = (const float*)d_in[3];
    const float* kw        = (const float*)d_in[4];
    const float* kb        = (const float*)d_in[5];
    const float* vw        = (const float*)d_in[6];
    const float* vb        = (const float*)d_in[7];
    const float* rw        = (const float*)d_in[8];
    const float* rb        = (const float*)d_in[9];
    float* out = (float*)d_out;

    const size_t NBL = (size_t)B_ * L_;        // 65536
    short* X   = (short*)d_ws;
    short* Qf  = X  + NBL * D_;
    short* Kf  = Qf + NBL * D_;
    short* Vf  = Kf + NBL * D_;
    short* Wbf = Vf + NBL * D_;                // 3 layers x 3 mats x 16384 bf16 (pre-swizzled)

    hipMemsetAsync(out, 0, out_size * sizeof(float), stream);
    k_form_x<<<dim3((NBL * D_ / 8) / 256), 256, 0, stream>>>(genotypes, emb, X);
    k_convw<<<dim3(24, 3), 256, 0, stream>>>(qw, kw, vw, Wbf);
    for (int layer = 0; layer < NL_; layer++) {
        int boff = layer * D_;
        k_qkv<<<dim3(1536), 256, 0, stream>>>(X, Wbf + (size_t)layer * 3 * 16384,
                                              qb + boff, kb + boff, vb + boff,
                                              Qf, Kf, Vf);
        k_attn<<<dim3(512), 256, 0, stream>>>(Qf, Kf, Vf, X, rw, rb, out,
                                              layer == NL_ - 1 ? 1 : 0);
    }
}

// Round 9
// 354.284 us; speedup vs baseline: 1.2150x; 1.0256x over previous
//
#include <hip/hip_runtime.h>
#include <hip/hip_bf16.h>

// Shapes
#define B_   32
#define L_   2048
#define D_   128
#define NL_  3
#define KVB  64
#define NKT  (L_ / KVB)         // 32

typedef __attribute__((ext_vector_type(8))) short short8;
typedef __attribute__((ext_vector_type(4))) float f32x4;
typedef __attribute__((ext_vector_type(16))) float f32x16;

__device__ __forceinline__ short f2bf(float f) {
    unsigned u = __builtin_bit_cast(unsigned, f);
    u += 0x7fffu + ((u >> 16) & 1u);          // RNE
    return (short)(u >> 16);
}
// pack two floats -> bf16 pair in one u32 (low = a, high = b), RNE
__device__ __forceinline__ unsigned pk2(float a, float b) {
    unsigned ua = __builtin_bit_cast(unsigned, a);
    ua += 0x7fffu + ((ua >> 16) & 1u);
    unsigned ub = __builtin_bit_cast(unsigned, b);
    ub += 0x7fffu + ((ub >> 16) & 1u);
    return (ua >> 16) | (ub & 0xffff0000u);
}
// swap halves across lane<32 / lane>=32 (m214 T12 pattern)
__device__ __forceinline__ void plswap(unsigned& a, unsigned& b) {
    asm volatile("v_permlane32_swap_b32 %0, %1" : "+v"(a), "+v"(b));
}

// async global -> LDS, 16 bytes per lane (dest must be linear: base + lane*16)
__device__ __forceinline__ void gll16(const void* g, void* l) {
    __builtin_amdgcn_global_load_lds(
        (__attribute__((address_space(1))) void*)(g),
        (__attribute__((address_space(3))) void*)(l), 16, 0, 0);
}

// Fragment-order global layouts (16B granule per lane):
//  Q/K: addr = b*512K + blk32*8K + dst*1K + lane*16
//       content: Row[blk32*32 + (lane&31)], d-elems dst*16 + (lane>>5)*8 .. +8
//  Vt:  addr = b*512K + kt*16K + k16*4K + d2*1K + lane*16
//       content: V^T[d = d2*32 + (lane&31)][l = kt*64 + k16*16 + (lane>>5)*8 .. +8]

// ---------------------------------------------------------------- form x
__global__ __launch_bounds__(256) void k_form_x(const float* __restrict__ g,
                                                const float* __restrict__ emb,
                                                short* __restrict__ X) {
    int tid = blockIdx.x * 256 + threadIdx.x;   // one thread = 8 elements
    int bl  = tid >> 4;
    int d8  = (tid & 15) << 3;
    int l   = bl & (L_ - 1);
    float gv = g[bl];
    const float4* e = reinterpret_cast<const float4*>(emb + (size_t)l * D_ + d8);
    float4 a = e[0], b = e[1];
    short8 r;
    r[0]=f2bf(a.x*gv); r[1]=f2bf(a.y*gv); r[2]=f2bf(a.z*gv); r[3]=f2bf(a.w*gv);
    r[4]=f2bf(b.x*gv); r[5]=f2bf(b.y*gv); r[6]=f2bf(b.z*gv); r[7]=f2bf(b.w*gv);
    *reinterpret_cast<short8*>(X + (size_t)tid * 8) = r;
}

// ---------------------------------------------------------------- weight convert
// fp32 W -> bf16, stored PRE-SWIZZLED so k_qkv can gll16 it linearly.
__global__ __launch_bounds__(256) void k_convw(const float* __restrict__ qw,
                                               const float* __restrict__ kw,
                                               const float* __restrict__ vw,
                                               short* __restrict__ Wbf) {
    const float* src = (blockIdx.y == 0) ? qw : (blockIdx.y == 1) ? kw : vw;
    int tid = blockIdx.x * 256 + threadIdx.x;   // 0..6143
    int layer = tid >> 11;
    int i = tid & 2047;
    int Lb = i * 16;
    int row = Lb >> 8, c = (Lb & 255) ^ ((row & 7) << 4);
    const float4* p = reinterpret_cast<const float4*>(src + (size_t)layer * 16384 + row * 128 + (c >> 1));
    float4 a = p[0], b = p[1];
    short8 s;
    s[0]=f2bf(a.x); s[1]=f2bf(a.y); s[2]=f2bf(a.z); s[3]=f2bf(a.w);
    s[4]=f2bf(b.x); s[5]=f2bf(b.y); s[6]=f2bf(b.z); s[7]=f2bf(b.w);
    size_t off = ((size_t)layer * 3 + blockIdx.y) * 16384;
    *reinterpret_cast<short8*>(Wbf + off + (size_t)i * 8) = s;
}

// ---------------------------------------------------------------- QKV GEMM
// Flat 1536-block grid, XCD-grouped. Outputs written in FRAGMENT ORDER.
__global__ __launch_bounds__(256, 2) void k_qkv(const short* __restrict__ X,
    const short* __restrict__ Wl,
    const float* __restrict__ bq, const float* __restrict__ bk, const float* __restrict__ bv,
    short* __restrict__ Qf, short* __restrict__ Kf, short* __restrict__ Vf) {
    __shared__ short xs[128 * 128];
    __shared__ short wsh[128 * 128];
    const int t = threadIdx.x;
    int flat = blockIdx.x, xcd = flat & 7, idx = flat >> 3;
    int mat = idx >> 6, rblk = xcd * 64 + (idx & 63);
    const float* bias = (mat == 0) ? bq : (mat == 1) ? bk : bv;
    const short* Wg = Wl + (size_t)mat * 16384;
    const size_t rowbase = (size_t)rblk * 128;

    const char* Xg = reinterpret_cast<const char*>(X) + rowbase * 256;
#pragma unroll
    for (int p = 0; p < 8; p++) {
        int Lb = (p * 256 + t) * 16;
        int row = Lb >> 8, c = Lb & 255;
        gll16(Xg + (size_t)row * 256 + (c ^ ((row & 7) << 4)),
              reinterpret_cast<char*>(xs) + Lb);
    }
#pragma unroll
    for (int p = 0; p < 8; p++) {
        int Lb = (p * 256 + t) * 16;
        gll16(reinterpret_cast<const char*>(Wg) + Lb,
              reinterpret_cast<char*>(wsh) + Lb);
    }
    __syncthreads();

    const int wave = t >> 6, lane = t & 63, g = lane >> 4, ln = lane & 15;
    const int bb2 = (int)(rowbase >> 11);      // batch
    const int l0  = (int)(rowbase & (L_ - 1)); // row within batch
    f32x4 acc[2][8];
#pragma unroll
    for (int mi = 0; mi < 2; mi++)
#pragma unroll
        for (int ni = 0; ni < 8; ni++) acc[mi][ni] = f32x4{0.f, 0.f, 0.f, 0.f};

    if (mat < 2) {
        // A = W (rows e), B = X (rows l) -> C[e][l]
#pragma unroll
        for (int kk = 0; kk < 4; kk++) {
            short8 aW[2];
#pragma unroll
            for (int mi = 0; mi < 2; mi++) {
                int row = wave * 32 + mi * 16 + ln;
                int byte = (row * 256 + kk * 64 + g * 16) ^ ((row & 7) << 4);
                aW[mi] = *reinterpret_cast<const short8*>(reinterpret_cast<const char*>(wsh) + byte);
            }
#pragma unroll
            for (int ni = 0; ni < 8; ni++) {
                int row = ni * 16 + ln;
                int byte = (row * 256 + kk * 64 + g * 16) ^ ((row & 7) << 4);
                short8 bX = *reinterpret_cast<const short8*>(reinterpret_cast<const char*>(xs) + byte);
                acc[0][ni] = __builtin_amdgcn_mfma_f32_16x16x32_bf16(aW[0], bX, acc[0][ni], 0, 0, 0);
                acc[1][ni] = __builtin_amdgcn_mfma_f32_16x16x32_bf16(aW[1], bX, acc[1][ni], 0, 0, 0);
            }
        }
        // store in fragment order: granule(blk32, dst, lane'), half-granule by (g&1)
        char* oc = reinterpret_cast<char*>((mat == 0) ? Qf : Kf) + ((size_t)bb2 << 19);
        int lidx_hi = ((g >> 1) & 1) << 5;     // d-half within granule lane index
#pragma unroll
        for (int mi = 0; mi < 2; mi++) {
            int e0 = wave * 32 + mi * 16 + g * 4;
            int dst = wave * 2 + mi;
            float4 b4 = *reinterpret_cast<const float4*>(bias + e0);
#pragma unroll
            for (int ni = 0; ni < 8; ni++) {
                unsigned lo = (unsigned short)f2bf(acc[mi][ni][0] + b4.x)
                            | ((unsigned)(unsigned short)f2bf(acc[mi][ni][1] + b4.y) << 16);
                unsigned hi2 = (unsigned short)f2bf(acc[mi][ni][2] + b4.z)
                            | ((unsigned)(unsigned short)f2bf(acc[mi][ni][3] + b4.w) << 16);
                int blk32 = (l0 >> 5) + (ni >> 1);
                int l31 = ((ni & 1) << 4) + ln;
                size_t off = ((size_t)(blk32 * 8 + dst) << 10)
                           + ((lidx_hi + l31) << 4) + ((g & 1) << 3);
                int2 pk; pk.x = (int)lo; pk.y = (int)hi2;
                *reinterpret_cast<int2*>(oc + off) = pk;
            }
        }
    } else {
        // V: A = X (rows l), B = W (rows e) -> C[l][e]
#pragma unroll
        for (int kk = 0; kk < 4; kk++) {
            short8 aX[2];
#pragma unroll
            for (int mi = 0; mi < 2; mi++) {
                int row = wave * 32 + mi * 16 + ln;
                int byte = (row * 256 + kk * 64 + g * 16) ^ ((row & 7) << 4);
                aX[mi] = *reinterpret_cast<const short8*>(reinterpret_cast<const char*>(xs) + byte);
            }
#pragma unroll
            for (int ni = 0; ni < 8; ni++) {
                int row = ni * 16 + ln;
                int byte = (row * 256 + kk * 64 + g * 16) ^ ((row & 7) << 4);
                short8 bW = *reinterpret_cast<const short8*>(reinterpret_cast<const char*>(wsh) + byte);
                acc[0][ni] = __builtin_amdgcn_mfma_f32_16x16x32_bf16(aX[0], bW, acc[0][ni], 0, 0, 0);
                acc[1][ni] = __builtin_amdgcn_mfma_f32_16x16x32_bf16(aX[1], bW, acc[1][ni], 0, 0, 0);
            }
        }
        // store in fragment order: granule(kt, k16, d2, lane'), half-granule by (g&1)
        char* oc = reinterpret_cast<char*>(Vf) + ((size_t)bb2 << 19);
#pragma unroll
        for (int ni = 0; ni < 8; ni++) {
            int d = ni * 16 + ln;
            float bvv = bias[d];
            int d2 = d >> 5, d31 = d & 31;
#pragma unroll
            for (int mi = 0; mi < 2; mi++) {
                unsigned lo = (unsigned short)f2bf(acc[mi][ni][0] + bvv)
                            | ((unsigned)(unsigned short)f2bf(acc[mi][ni][1] + bvv) << 16);
                unsigned hi2 = (unsigned short)f2bf(acc[mi][ni][2] + bvv)
                            | ((unsigned)(unsigned short)f2bf(acc[mi][ni][3] + bvv) << 16);
                int lglob = l0 + wave * 32 + mi * 16 + g * 4;
                int kt = lglob >> 6, k16 = (lglob >> 4) & 3, lhi = (lglob >> 3) & 1;
                size_t off = ((size_t)kt << 14) + (k16 << 12) + (d2 << 10)
                           + ((lhi * 32 + d31) << 4) + ((g & 1) << 3);
                int2 pk; pk.x = (int)lo; pk.y = (int)hi2;
                *reinterpret_cast<int2*>(oc + off) = pk;
            }
        }
    }
}

// ---------------------------------------------------------------- flash attention
// 32x32x16 MFMA; swapped QK^T; in-register P via permlane32_swap; KVBLK=64.
// Fragment-order global -> contiguous gll16 staging AND lane-linear LDS reads.
// R9: 48 KB LDS (K double-buffered, V single-buffered) -> 3 blocks/CU (+50% TLP).
// V(t+1) staged after the end-of-iter barrier (PV(t) done), lands under QK(t+1).
__global__ __launch_bounds__(256, 3) void k_attn(const short* __restrict__ Qf,
                                                 const short* __restrict__ Kf,
                                                 const short* __restrict__ Vf,
                                                 short* __restrict__ Xo,
                                                 const float* __restrict__ rw,
                                                 const float* __restrict__ rb,
                                                 float* __restrict__ out,
                                                 int fuse) {
    __shared__ short Ks[2][KVB * 128];    // 2 x 16 KB, fragment order
    __shared__ short Vts[128 * KVB];      // 16 KB, fragment order (single buffer)
    const int t = threadIdx.x, w = t >> 6, lane = t & 63;
    const int hi = lane >> 5, c5 = lane & 31;
    // XCD-aware remap: each XCD owns 4 batches x 16 q-tiles (K/V L2-resident)
    int flat = blockIdx.x;
    int xcd = flat & 7, idx = flat >> 3;
    int b = xcd * 4 + (idx >> 4), qt = idx & 15;
    const size_t qbase = (size_t)b * L_ + qt * 128;

    // Q fragments -> registers (contiguous 1KB per load: fragment-order global)
    const char* Qg = reinterpret_cast<const char*>(Qf) + ((size_t)b << 19);
    short8 qf[8];
#pragma unroll
    for (int dst = 0; dst < 8; dst++)
        qf[dst] = *reinterpret_cast<const short8*>(
            Qg + (((size_t)(qt * 4 + w) * 8 + dst) << 10) + lane * 16);
    __builtin_amdgcn_sched_barrier(0);    // pin Q loads before staging (vmcnt accounting)

    const char* Kg = reinterpret_cast<const char*>(Kf) + ((size_t)b << 19);
    const char* Vg = reinterpret_cast<const char*>(Vf) + ((size_t)b << 19);

    // stage helpers: pure linear copy (global fragment-order -> LDS), 4 loads each
    auto stageK = [&](int kt, int buf) {
#pragma unroll
        for (int p = 0; p < 4; p++) {
            int Lb = (p * 256 + t) * 16;
            gll16(Kg + ((size_t)kt << 14) + Lb, reinterpret_cast<char*>(Ks[buf]) + Lb);
        }
    };
    auto stageV = [&](int kt) {
#pragma unroll
        for (int p = 0; p < 4; p++) {
            int Lb = (p * 256 + t) * 16;
            gll16(Vg + ((size_t)kt << 14) + Lb, reinterpret_cast<char*>(Vts) + Lb);
        }
    };

    stageK(0, 0);
    stageV(0);
    stageK(1, 1);

    f32x16 o[4];
#pragma unroll
    for (int d2 = 0; d2 < 4; d2++)
#pragma unroll
        for (int r = 0; r < 16; r++) o[d2][r] = 0.f;
    float lsum = 0.f;

    for (int kt = 0; kt < NKT; kt++) {
        // K(t), V(t) landed; K(t+1)'s 4 loads stay in flight
        if (kt < NKT - 1) asm volatile("s_waitcnt vmcnt(4)" ::: "memory");
        else              asm volatile("s_waitcnt vmcnt(0)" ::: "memory");
        __builtin_amdgcn_sched_barrier(0);
        __builtin_amdgcn_s_barrier();           // all waves' portions landed

        const char* Kb8 = reinterpret_cast<const char*>(Ks[kt & 1]) + lane * 16;
        const char* Vb8 = reinterpret_cast<const char*>(Vts) + lane * 16;

        // S^T = K.Q^T : two 32x32 k-tiles, 8 d-steps each
        f32x16 s0, s1;
#pragma unroll
        for (int r = 0; r < 16; r++) { s0[r] = 0.f; s1[r] = 0.f; }
        __builtin_amdgcn_s_setprio(1);
#pragma unroll
        for (int dst = 0; dst < 8; dst++) {
            short8 kf0 = *reinterpret_cast<const short8*>(Kb8 + dst * 1024);
            short8 kf1 = *reinterpret_cast<const short8*>(Kb8 + 8192 + dst * 1024);
            s0 = __builtin_amdgcn_mfma_f32_32x32x16_bf16(kf0, qf[dst], s0, 0, 0, 0);
            s1 = __builtin_amdgcn_mfma_f32_32x32x16_bf16(kf1, qf[dst], s1, 0, 0, 0);
        }
        __builtin_amdgcn_s_setprio(0);

        // exp (unshifted) + in-register P-frag assembly via permlane32_swap
        float e0[16], e1[16];
#pragma unroll
        for (int r = 0; r < 16; r++) { e0[r] = __expf(s0[r]); e1[r] = __expf(s1[r]); }
#pragma unroll
        for (int r = 0; r < 16; r++) lsum += e0[r] + e1[r];

        short8 pa[4];
#pragma unroll
        for (int kt16 = 0; kt16 < 4; kt16++) {
            const float* e = (kt16 < 2) ? e0 : e1;
            int rb2 = (kt16 & 1) * 8;
            unsigned w01 = pk2(e[rb2 + 0], e[rb2 + 1]);
            unsigned w23 = pk2(e[rb2 + 2], e[rb2 + 3]);
            unsigned w45 = pk2(e[rb2 + 4], e[rb2 + 5]);
            unsigned w67 = pk2(e[rb2 + 6], e[rb2 + 7]);
            plswap(w01, w45);
            plswap(w23, w67);
            uint4 fr; fr.x = w01; fr.y = w23; fr.z = w45; fr.w = w67;
            pa[kt16] = __builtin_bit_cast(short8, fr);
        }

        // O += P.V : 4 k16-slices x 4 d-blocks
        __builtin_amdgcn_s_setprio(1);
#pragma unroll
        for (int kt16 = 0; kt16 < 4; kt16++) {
#pragma unroll
            for (int d2 = 0; d2 < 4; d2++) {
                short8 vf = *reinterpret_cast<const short8*>(Vb8 + kt16 * 4096 + d2 * 1024);
                o[d2] = __builtin_amdgcn_mfma_f32_32x32x16_bf16(pa[kt16], vf, o[d2], 0, 0, 0);
            }
        }
        __builtin_amdgcn_s_setprio(0);

        __builtin_amdgcn_sched_barrier(0);
        __builtin_amdgcn_s_barrier();           // all waves done with V(t) and K-buf kt&1
        if (kt + 1 < NKT) stageV(kt + 1);       // overwrite V (safe: PV(t) done)
        if (kt + 2 < NKT) stageK(kt + 2, kt & 1);
    }

    // denominators: lane holds partial for q=c5 over its hi-half k-set
    lsum += __shfl_xor(lsum, 32, 64);           // full sum for q=c5 in all lanes

    if (!fuse) {
#pragma unroll
        for (int reg = 0; reg < 16; reg++) {
            int crow = (reg & 3) + 8 * (reg >> 2) + 4 * hi;   // q-local
            float inv = 1.0f / __shfl(lsum, crow, 64);
            size_t rowg = qbase + w * 32 + crow;
#pragma unroll
            for (int d2 = 0; d2 < 4; d2++)
                Xo[rowg * D_ + d2 * 32 + c5] = f2bf(o[d2][reg] * inv);
        }
    } else {
        float part = 0.f;
#pragma unroll
        for (int reg = 0; reg < 16; reg++) {
            int crow = (reg & 3) + 8 * (reg >> 2) + 4 * hi;
            float inv = 1.0f / __shfl(lsum, crow, 64);
            size_t rowg = (size_t)(qt * 128 + w * 32 + crow) * D_;
#pragma unroll
            for (int d2 = 0; d2 < 4; d2++)
                part += (o[d2][reg] * inv) * rw[rowg + d2 * 32 + c5];
        }
#pragma unroll
        for (int off = 32; off > 0; off >>= 1) part += __shfl_xor(part, off, 64);
        if (lane == 0) atomicAdd(out + b, part);
        if (qt == 0 && t == 0) atomicAdd(out + b, rb[0]);
    }
}

// ---------------------------------------------------------------- launch
extern "C" void kernel_launch(void* const* d_in, const int* in_sizes, int n_in,
                              void* d_out, int out_size, void* d_ws, size_t ws_size,
                              hipStream_t stream) {
    const float* genotypes = (const float*)d_in[0];
    const float* emb       = (const float*)d_in[1];
    const float* qw        = (const float*)d_in[2];
    const float* qb        = (const float*)d_in[3];
    const float* kw        = (const float*)d_in[4];
    const float* kb        = (const float*)d_in[5];
    const float* vw        = (const float*)d_in[6];
    const float* vb        = (const float*)d_in[7];
    const float* rw        = (const float*)d_in[8];
    const float* rb        = (const float*)d_in[9];
    float* out = (float*)d_out;

    const size_t NBL = (size_t)B_ * L_;        // 65536
    short* X   = (short*)d_ws;
    short* Qf  = X  + NBL * D_;
    short* Kf  = Qf + NBL * D_;
    short* Vf  = Kf + NBL * D_;
    short* Wbf = Vf + NBL * D_;                // 3 layers x 3 mats x 16384 bf16 (pre-swizzled)

    hipMemsetAsync(out, 0, out_size * sizeof(float), stream);
    k_form_x<<<dim3((NBL * D_ / 8) / 256), 256, 0, stream>>>(genotypes, emb, X);
    k_convw<<<dim3(24, 3), 256, 0, stream>>>(qw, kw, vw, Wbf);
    for (int layer = 0; layer < NL_; layer++) {
        int boff = layer * D_;
        k_qkv<<<dim3(1536), 256, 0, stream>>>(X, Wbf + (size_t)layer * 3 * 16384,
                                              qb + boff, kb + boff, vb + boff,
                                              Qf, Kf, Vf);
        k_attn<<<dim3(512), 256, 0, stream>>>(Qf, Kf, Vf, X, rw, rb, out,
                                              layer == NL_ - 1 ? 1 : 0);
    }
}

// Round 10
// 339.027 us; speedup vs baseline: 1.2697x; 1.0450x over previous
//
#include <hip/hip_runtime.h>
#include <hip/hip_bf16.h>

// Shapes
#define B_   32
#define L_   2048
#define D_   128
#define NL_  3
#define KVB  64
#define NKT  (L_ / KVB)         // 32

typedef __attribute__((ext_vector_type(8))) short short8;
typedef __attribute__((ext_vector_type(4))) float f32x4;
typedef __attribute__((ext_vector_type(16))) float f32x16;

__device__ __forceinline__ short f2bf(float f) {
    unsigned u = __builtin_bit_cast(unsigned, f);
    u += 0x7fffu + ((u >> 16) & 1u);          // RNE
    return (short)(u >> 16);
}
// v_exp_f32 computes 2^x (hazards handled by post-RA hazard recognizer)
__device__ __forceinline__ float exp2g(float x) {
    float r; asm("v_exp_f32 %0, %1" : "=v"(r) : "v"(x)); return r;
}
// pack two f32 -> 2x bf16 in one u32 (low=a, high=b), RNE
__device__ __forceinline__ unsigned cvtpk(float a, float b) {
    unsigned r; asm("v_cvt_pk_bf16_f32 %0, %1, %2" : "=v"(r) : "v"(a), "v"(b)); return r;
}
// swap halves across lane<32 / lane>=32 (m214 T12 pattern)
__device__ __forceinline__ void plswap(unsigned& a, unsigned& b) {
    asm volatile("v_permlane32_swap_b32 %0, %1" : "+v"(a), "+v"(b));
}

// async global -> LDS, 16 bytes per lane (dest must be linear: base + lane*16)
__device__ __forceinline__ void gll16(const void* g, void* l) {
    __builtin_amdgcn_global_load_lds(
        (__attribute__((address_space(1))) void*)(g),
        (__attribute__((address_space(3))) void*)(l), 16, 0, 0);
}

// Fragment-order global layouts (16B granule per lane):
//  Q/K: addr = b*512K + blk32*8K + dst*1K + lane*16
//  Vt:  addr = b*512K + kt*16K + k16*4K + d2*1K + lane*16

// ---------------------------------------------------------------- form x
__global__ __launch_bounds__(256) void k_form_x(const float* __restrict__ g,
                                                const float* __restrict__ emb,
                                                short* __restrict__ X) {
    int tid = blockIdx.x * 256 + threadIdx.x;   // one thread = 8 elements
    int bl  = tid >> 4;
    int d8  = (tid & 15) << 3;
    int l   = bl & (L_ - 1);
    float gv = g[bl];
    const float4* e = reinterpret_cast<const float4*>(emb + (size_t)l * D_ + d8);
    float4 a = e[0], b = e[1];
    short8 r;
    r[0]=f2bf(a.x*gv); r[1]=f2bf(a.y*gv); r[2]=f2bf(a.z*gv); r[3]=f2bf(a.w*gv);
    r[4]=f2bf(b.x*gv); r[5]=f2bf(b.y*gv); r[6]=f2bf(b.z*gv); r[7]=f2bf(b.w*gv);
    *reinterpret_cast<short8*>(X + (size_t)tid * 8) = r;
}

// ---------------------------------------------------------------- weight convert
__global__ __launch_bounds__(256) void k_convw(const float* __restrict__ qw,
                                               const float* __restrict__ kw,
                                               const float* __restrict__ vw,
                                               short* __restrict__ Wbf) {
    const float* src = (blockIdx.y == 0) ? qw : (blockIdx.y == 1) ? kw : vw;
    int tid = blockIdx.x * 256 + threadIdx.x;   // 0..6143
    int layer = tid >> 11;
    int i = tid & 2047;
    int Lb = i * 16;
    int row = Lb >> 8, c = (Lb & 255) ^ ((row & 7) << 4);
    const float4* p = reinterpret_cast<const float4*>(src + (size_t)layer * 16384 + row * 128 + (c >> 1));
    float4 a = p[0], b = p[1];
    short8 s;
    s[0]=f2bf(a.x); s[1]=f2bf(a.y); s[2]=f2bf(a.z); s[3]=f2bf(a.w);
    s[4]=f2bf(b.x); s[5]=f2bf(b.y); s[6]=f2bf(b.z); s[7]=f2bf(b.w);
    size_t off = ((size_t)layer * 3 + blockIdx.y) * 16384;
    *reinterpret_cast<short8*>(Wbf + off + (size_t)i * 8) = s;
}

// ---------------------------------------------------------------- QKV GEMM
// Flat 1536-block grid, XCD-grouped. Outputs written in FRAGMENT ORDER.
// Q is pre-scaled by log2(e) so attention can use raw v_exp_f32 (2^x).
__global__ __launch_bounds__(256, 2) void k_qkv(const short* __restrict__ X,
    const short* __restrict__ Wl,
    const float* __restrict__ bq, const float* __restrict__ bk, const float* __restrict__ bv,
    short* __restrict__ Qf, short* __restrict__ Kf, short* __restrict__ Vf) {
    __shared__ short xs[128 * 128];
    __shared__ short wsh[128 * 128];
    const int t = threadIdx.x;
    int flat = blockIdx.x, xcd = flat & 7, idx = flat >> 3;
    int mat = idx >> 6, rblk = xcd * 64 + (idx & 63);
    const float* bias = (mat == 0) ? bq : (mat == 1) ? bk : bv;
    const short* Wg = Wl + (size_t)mat * 16384;
    const size_t rowbase = (size_t)rblk * 128;

    const char* Xg = reinterpret_cast<const char*>(X) + rowbase * 256;
#pragma unroll
    for (int p = 0; p < 8; p++) {
        int Lb = (p * 256 + t) * 16;
        int row = Lb >> 8, c = Lb & 255;
        gll16(Xg + (size_t)row * 256 + (c ^ ((row & 7) << 4)),
              reinterpret_cast<char*>(xs) + Lb);
    }
#pragma unroll
    for (int p = 0; p < 8; p++) {
        int Lb = (p * 256 + t) * 16;
        gll16(reinterpret_cast<const char*>(Wg) + Lb,
              reinterpret_cast<char*>(wsh) + Lb);
    }
    __syncthreads();

    const int wave = t >> 6, lane = t & 63, g = lane >> 4, ln = lane & 15;
    const int bb2 = (int)(rowbase >> 11);      // batch
    const int l0  = (int)(rowbase & (L_ - 1)); // row within batch
    f32x4 acc[2][8];
#pragma unroll
    for (int mi = 0; mi < 2; mi++)
#pragma unroll
        for (int ni = 0; ni < 8; ni++) acc[mi][ni] = f32x4{0.f, 0.f, 0.f, 0.f};

    if (mat < 2) {
        // A = W (rows e), B = X (rows l) -> C[e][l]
#pragma unroll
        for (int kk = 0; kk < 4; kk++) {
            short8 aW[2];
#pragma unroll
            for (int mi = 0; mi < 2; mi++) {
                int row = wave * 32 + mi * 16 + ln;
                int byte = (row * 256 + kk * 64 + g * 16) ^ ((row & 7) << 4);
                aW[mi] = *reinterpret_cast<const short8*>(reinterpret_cast<const char*>(wsh) + byte);
            }
#pragma unroll
            for (int ni = 0; ni < 8; ni++) {
                int row = ni * 16 + ln;
                int byte = (row * 256 + kk * 64 + g * 16) ^ ((row & 7) << 4);
                short8 bX = *reinterpret_cast<const short8*>(reinterpret_cast<const char*>(xs) + byte);
                acc[0][ni] = __builtin_amdgcn_mfma_f32_16x16x32_bf16(aW[0], bX, acc[0][ni], 0, 0, 0);
                acc[1][ni] = __builtin_amdgcn_mfma_f32_16x16x32_bf16(aW[1], bX, acc[1][ni], 0, 0, 0);
            }
        }
        const float qscale = (mat == 0) ? 1.4426950408889634f : 1.0f;  // log2(e) folded into Q
        char* oc = reinterpret_cast<char*>((mat == 0) ? Qf : Kf) + ((size_t)bb2 << 19);
        int lidx_hi = ((g >> 1) & 1) << 5;
#pragma unroll
        for (int mi = 0; mi < 2; mi++) {
            int e0 = wave * 32 + mi * 16 + g * 4;
            int dst = wave * 2 + mi;
            float4 b4 = *reinterpret_cast<const float4*>(bias + e0);
#pragma unroll
            for (int ni = 0; ni < 8; ni++) {
                unsigned lo = (unsigned short)f2bf((acc[mi][ni][0] + b4.x) * qscale)
                            | ((unsigned)(unsigned short)f2bf((acc[mi][ni][1] + b4.y) * qscale) << 16);
                unsigned hi2 = (unsigned short)f2bf((acc[mi][ni][2] + b4.z) * qscale)
                            | ((unsigned)(unsigned short)f2bf((acc[mi][ni][3] + b4.w) * qscale) << 16);
                int blk32 = (l0 >> 5) + (ni >> 1);
                int l31 = ((ni & 1) << 4) + ln;
                size_t off = ((size_t)(blk32 * 8 + dst) << 10)
                           + ((lidx_hi + l31) << 4) + ((g & 1) << 3);
                int2 pk; pk.x = (int)lo; pk.y = (int)hi2;
                *reinterpret_cast<int2*>(oc + off) = pk;
            }
        }
    } else {
        // V: A = X (rows l), B = W (rows e) -> C[l][e]
#pragma unroll
        for (int kk = 0; kk < 4; kk++) {
            short8 aX[2];
#pragma unroll
            for (int mi = 0; mi < 2; mi++) {
                int row = wave * 32 + mi * 16 + ln;
                int byte = (row * 256 + kk * 64 + g * 16) ^ ((row & 7) << 4);
                aX[mi] = *reinterpret_cast<const short8*>(reinterpret_cast<const char*>(xs) + byte);
            }
#pragma unroll
            for (int ni = 0; ni < 8; ni++) {
                int row = ni * 16 + ln;
                int byte = (row * 256 + kk * 64 + g * 16) ^ ((row & 7) << 4);
                short8 bW = *reinterpret_cast<const short8*>(reinterpret_cast<const char*>(wsh) + byte);
                acc[0][ni] = __builtin_amdgcn_mfma_f32_16x16x32_bf16(aX[0], bW, acc[0][ni], 0, 0, 0);
                acc[1][ni] = __builtin_amdgcn_mfma_f32_16x16x32_bf16(aX[1], bW, acc[1][ni], 0, 0, 0);
            }
        }
        char* oc = reinterpret_cast<char*>(Vf) + ((size_t)bb2 << 19);
#pragma unroll
        for (int ni = 0; ni < 8; ni++) {
            int d = ni * 16 + ln;
            float bvv = bias[d];
            int d2 = d >> 5, d31 = d & 31;
#pragma unroll
            for (int mi = 0; mi < 2; mi++) {
                unsigned lo = (unsigned short)f2bf(acc[mi][ni][0] + bvv)
                            | ((unsigned)(unsigned short)f2bf(acc[mi][ni][1] + bvv) << 16);
                unsigned hi2 = (unsigned short)f2bf(acc[mi][ni][2] + bvv)
                            | ((unsigned)(unsigned short)f2bf(acc[mi][ni][3] + bvv) << 16);
                int lglob = l0 + wave * 32 + mi * 16 + g * 4;
                int kt = lglob >> 6, k16 = (lglob >> 4) & 3, lhi = (lglob >> 3) & 1;
                size_t off = ((size_t)kt << 14) + (k16 << 12) + (d2 << 10)
                           + ((lhi * 32 + d31) << 4) + ((g & 1) << 3);
                int2 pk; pk.x = (int)lo; pk.y = (int)hi2;
                *reinterpret_cast<int2*>(oc + off) = pk;
            }
        }
    }
}

// ---------------------------------------------------------------- flash attention
// T15 pipeline: per iter QK(t) -> PV(t-1) [MFMA] || softmax(t) [VALU].
// V triple-buffered (slot (t+2)%3 freed by PV(t-1) in same iter). K double-buffered.
// LDS 80 KB = 2 blocks/CU (grid is 512 = 2/CU anyway).
__global__ __launch_bounds__(256, 2) void k_attn(const short* __restrict__ Qf,
                                                 const short* __restrict__ Kf,
                                                 const short* __restrict__ Vf,
                                                 short* __restrict__ Xo,
                                                 const float* __restrict__ rw,
                                                 const float* __restrict__ rb,
                                                 float* __restrict__ out,
                                                 int fuse) {
    __shared__ short Ks[2][KVB * 128];    // 2 x 16 KB, fragment order
    __shared__ short Vts[3][128 * KVB];   // 3 x 16 KB, fragment order
    const int t = threadIdx.x, w = t >> 6, lane = t & 63;
    const int hi = lane >> 5, c5 = lane & 31;
    int flat = blockIdx.x;
    int xcd = flat & 7, idx = flat >> 3;
    int b = xcd * 4 + (idx >> 4), qt = idx & 15;
    const size_t qbase = (size_t)b * L_ + qt * 128;

    // Q fragments -> registers (contiguous 1KB per load)
    const char* Qg = reinterpret_cast<const char*>(Qf) + ((size_t)b << 19);
    short8 qf[8];
#pragma unroll
    for (int dst = 0; dst < 8; dst++)
        qf[dst] = *reinterpret_cast<const short8*>(
            Qg + (((size_t)(qt * 4 + w) * 8 + dst) << 10) + lane * 16);
    __builtin_amdgcn_sched_barrier(0);    // pin Q loads before staging (vmcnt accounting)

    const char* Kg = reinterpret_cast<const char*>(Kf) + ((size_t)b << 19);
    const char* Vg = reinterpret_cast<const char*>(Vf) + ((size_t)b << 19);

    auto stageK = [&](int kt) {
#pragma unroll
        for (int p = 0; p < 4; p++) {
            int Lb = (p * 256 + t) * 16;
            gll16(Kg + ((size_t)kt << 14) + Lb, reinterpret_cast<char*>(Ks[kt & 1]) + Lb);
        }
    };
    auto stageV = [&](int kt) {
#pragma unroll
        for (int p = 0; p < 4; p++) {
            int Lb = (p * 256 + t) * 16;
            gll16(Vg + ((size_t)kt << 14) + Lb, reinterpret_cast<char*>(Vts[kt % 3]) + Lb);
        }
    };

    stageK(0); stageV(0); stageK(1); stageV(1);

    f32x16 o[4];
#pragma unroll
    for (int d2 = 0; d2 < 4; d2++)
#pragma unroll
        for (int r = 0; r < 16; r++) o[d2][r] = 0.f;
    float lsum = 0.f;
    short8 pa[4];                         // P fragments of the PREVIOUS iter

    // softmax: s -> e (2^s, Q pre-scaled), lsum, pa via cvt_pk + permlane32_swap
    auto softmax = [&](const f32x16& s0, const f32x16& s1) {
        float e0[16], e1[16];
#pragma unroll
        for (int r = 0; r < 16; r++) { e0[r] = exp2g(s0[r]); e1[r] = exp2g(s1[r]); }
#pragma unroll
        for (int r = 0; r < 16; r++) lsum += e0[r] + e1[r];
#pragma unroll
        for (int kt16 = 0; kt16 < 4; kt16++) {
            const float* e = (kt16 < 2) ? e0 : e1;
            int rb2 = (kt16 & 1) * 8;
            unsigned w01 = cvtpk(e[rb2 + 0], e[rb2 + 1]);
            unsigned w23 = cvtpk(e[rb2 + 2], e[rb2 + 3]);
            unsigned w45 = cvtpk(e[rb2 + 4], e[rb2 + 5]);
            unsigned w67 = cvtpk(e[rb2 + 6], e[rb2 + 7]);
            plswap(w01, w45);
            plswap(w23, w67);
            uint4 fr; fr.x = w01; fr.y = w23; fr.z = w45; fr.w = w67;
            pa[kt16] = __builtin_bit_cast(short8, fr);
        }
    };
    auto qk = [&](int kt, f32x16& s0, f32x16& s1) {
        const char* Kb8 = reinterpret_cast<const char*>(Ks[kt & 1]) + lane * 16;
#pragma unroll
        for (int r = 0; r < 16; r++) { s0[r] = 0.f; s1[r] = 0.f; }
        __builtin_amdgcn_s_setprio(1);
#pragma unroll
        for (int dst = 0; dst < 8; dst++) {
            short8 kf0 = *reinterpret_cast<const short8*>(Kb8 + dst * 1024);
            short8 kf1 = *reinterpret_cast<const short8*>(Kb8 + 8192 + dst * 1024);
            s0 = __builtin_amdgcn_mfma_f32_32x32x16_bf16(kf0, qf[dst], s0, 0, 0, 0);
            s1 = __builtin_amdgcn_mfma_f32_32x32x16_bf16(kf1, qf[dst], s1, 0, 0, 0);
        }
        __builtin_amdgcn_s_setprio(0);
    };
    auto pv = [&](int kt) {               // O += P(kt).V(kt), pa holds P(kt)
        const char* Vb8 = reinterpret_cast<const char*>(Vts[kt % 3]) + lane * 16;
        __builtin_amdgcn_s_setprio(1);
#pragma unroll
        for (int kt16 = 0; kt16 < 4; kt16++) {
#pragma unroll
            for (int d2 = 0; d2 < 4; d2++) {
                short8 vf = *reinterpret_cast<const short8*>(Vb8 + kt16 * 4096 + d2 * 1024);
                o[d2] = __builtin_amdgcn_mfma_f32_32x32x16_bf16(pa[kt16], vf, o[d2], 0, 0, 0);
            }
        }
        __builtin_amdgcn_s_setprio(0);
    };

    // ---- peeled iter 0: QK(0) + softmax(0), no PV
    {
        asm volatile("s_waitcnt vmcnt(8)" ::: "memory");
        __builtin_amdgcn_sched_barrier(0);
        __builtin_amdgcn_s_barrier();
        f32x16 s0, s1;
        qk(0, s0, s1);
        softmax(s0, s1);
        __builtin_amdgcn_sched_barrier(0);
        __builtin_amdgcn_s_barrier();
        stageV(2); stageK(2);
    }
    // ---- main loop: QK(kt); PV(kt-1) || softmax(kt)
    for (int kt = 1; kt < NKT; kt++) {
        if (kt < NKT - 1) asm volatile("s_waitcnt vmcnt(8)" ::: "memory");
        else              asm volatile("s_waitcnt vmcnt(0)" ::: "memory");
        __builtin_amdgcn_sched_barrier(0);
        __builtin_amdgcn_s_barrier();
        f32x16 s0, s1;
        qk(kt, s0, s1);
        pv(kt - 1);                        // MFMA, independent of s0/s1
        softmax(s0, s1);                   // VALU, scheduler interleaves into PV shadow
        __builtin_amdgcn_sched_barrier(0);
        __builtin_amdgcn_s_barrier();
        if (kt + 2 < NKT) { stageV(kt + 2); stageK(kt + 2); }
    }
    pv(NKT - 1);                           // final PV (V slot intact, loads drained)

    // denominators
    lsum += __shfl_xor(lsum, 32, 64);

    if (!fuse) {
#pragma unroll
        for (int reg = 0; reg < 16; reg++) {
            int crow = (reg & 3) + 8 * (reg >> 2) + 4 * hi;
            float inv = 1.0f / __shfl(lsum, crow, 64);
            size_t rowg = qbase + w * 32 + crow;
#pragma unroll
            for (int d2 = 0; d2 < 4; d2++)
                Xo[rowg * D_ + d2 * 32 + c5] = f2bf(o[d2][reg] * inv);
        }
    } else {
        float part = 0.f;
#pragma unroll
        for (int reg = 0; reg < 16; reg++) {
            int crow = (reg & 3) + 8 * (reg >> 2) + 4 * hi;
            float inv = 1.0f / __shfl(lsum, crow, 64);
            size_t rowg = (size_t)(qt * 128 + w * 32 + crow) * D_;
#pragma unroll
            for (int d2 = 0; d2 < 4; d2++)
                part += (o[d2][reg] * inv) * rw[rowg + d2 * 32 + c5];
        }
#pragma unroll
        for (int off = 32; off > 0; off >>= 1) part += __shfl_xor(part, off, 64);
        if (lane == 0) atomicAdd(out + b, part);
        if (qt == 0 && t == 0) atomicAdd(out + b, rb[0]);
    }
}

// ---------------------------------------------------------------- launch
extern "C" void kernel_launch(void* const* d_in, const int* in_sizes, int n_in,
                              void* d_out, int out_size, void* d_ws, size_t ws_size,
                              hipStream_t stream) {
    const float* genotypes = (const float*)d_in[0];
    const float* emb       = (const float*)d_in[1];
    const float* qw        = (const float*)d_in[2];
    const float* qb        = (const float*)d_in[3];
    const float* kw        = (const float*)d_in[4];
    const float* kb        = (const float*)d_in[5];
    const float* vw        = (const float*)d_in[6];
    const float* vb        = (const float*)d_in[7];
    const float* rw        = (const float*)d_in[8];
    const float* rb        = (const float*)d_in[9];
    float* out = (float*)d_out;

    const size_t NBL = (size_t)B_ * L_;        // 65536
    short* X   = (short*)d_ws;
    short* Qf  = X  + NBL * D_;
    short* Kf  = Qf + NBL * D_;
    short* Vf  = Kf + NBL * D_;
    short* Wbf = Vf + NBL * D_;                // 3 layers x 3 mats x 16384 bf16 (pre-swizzled)

    hipMemsetAsync(out, 0, out_size * sizeof(float), stream);
    k_form_x<<<dim3((NBL * D_ / 8) / 256), 256, 0, stream>>>(genotypes, emb, X);
    k_convw<<<dim3(24, 3), 256, 0, stream>>>(qw, kw, vw, Wbf);
    for (int layer = 0; layer < NL_; layer++) {
        int boff = layer * D_;
        k_qkv<<<dim3(1536), 256, 0, stream>>>(X, Wbf + (size_t)layer * 3 * 16384,
                                              qb + boff, kb + boff, vb + boff,
                                              Qf, Kf, Vf);
        k_attn<<<dim3(512), 256, 0, stream>>>(Qf, Kf, Vf, X, rw, rb, out,
                                              layer == NL_ - 1 ? 1 : 0);
    }
}

// Round 11
// 328.120 us; speedup vs baseline: 1.3119x; 1.0332x over previous
//
#include <hip/hip_runtime.h>
#include <hip/hip_bf16.h>

// Shapes
#define B_   32
#define L_   2048
#define D_   128
#define NL_  3
#define KVB  64
#define NKT  (L_ / KVB)         // 32

typedef __attribute__((ext_vector_type(8))) short short8;
typedef __attribute__((ext_vector_type(4))) float f32x4;
typedef __attribute__((ext_vector_type(16))) float f32x16;

__device__ __forceinline__ short f2bf(float f) {
    unsigned u = __builtin_bit_cast(unsigned, f);
    u += 0x7fffu + ((u >> 16) & 1u);          // RNE
    return (short)(u >> 16);
}
// v_exp_f32 computes 2^x
__device__ __forceinline__ float exp2g(float x) {
    float r; asm("v_exp_f32 %0, %1" : "=v"(r) : "v"(x)); return r;
}
// pack two f32 -> 2x bf16 in one u32 (low=a, high=b), RNE
__device__ __forceinline__ unsigned cvtpk(float a, float b) {
    unsigned r; asm("v_cvt_pk_bf16_f32 %0, %1, %2" : "=v"(r) : "v"(a), "v"(b)); return r;
}
// swap halves across lane<32 / lane>=32 (m214 T12 pattern)
__device__ __forceinline__ void plswap(unsigned& a, unsigned& b) {
    asm volatile("v_permlane32_swap_b32 %0, %1" : "+v"(a), "+v"(b));
}

// async global -> LDS, 16 bytes per lane (dest must be linear: base + lane*16)
__device__ __forceinline__ void gll16(const void* g, void* l) {
    __builtin_amdgcn_global_load_lds(
        (__attribute__((address_space(1))) void*)(g),
        (__attribute__((address_space(3))) void*)(l), 16, 0, 0);
}

// Fragment-order global layouts (16B granule per lane):
//  Q/K: addr = b*512K + blk32*8K + dst*1K + lane*16
//  Vt:  addr = b*512K + kt*16K + k16*4K + d2*1K + lane*16

// ---------------------------------------------------------------- form x
__global__ __launch_bounds__(256) void k_form_x(const float* __restrict__ g,
                                                const float* __restrict__ emb,
                                                short* __restrict__ X) {
    int tid = blockIdx.x * 256 + threadIdx.x;   // one thread = 8 elements
    int bl  = tid >> 4;
    int d8  = (tid & 15) << 3;
    int l   = bl & (L_ - 1);
    float gv = g[bl];
    const float4* e = reinterpret_cast<const float4*>(emb + (size_t)l * D_ + d8);
    float4 a = e[0], b = e[1];
    short8 r;
    r[0]=f2bf(a.x*gv); r[1]=f2bf(a.y*gv); r[2]=f2bf(a.z*gv); r[3]=f2bf(a.w*gv);
    r[4]=f2bf(b.x*gv); r[5]=f2bf(b.y*gv); r[6]=f2bf(b.z*gv); r[7]=f2bf(b.w*gv);
    *reinterpret_cast<short8*>(X + (size_t)tid * 8) = r;
}

// ---------------------------------------------------------------- weight convert
__global__ __launch_bounds__(256) void k_convw(const float* __restrict__ qw,
                                               const float* __restrict__ kw,
                                               const float* __restrict__ vw,
                                               short* __restrict__ Wbf) {
    const float* src = (blockIdx.y == 0) ? qw : (blockIdx.y == 1) ? kw : vw;
    int tid = blockIdx.x * 256 + threadIdx.x;   // 0..6143
    int layer = tid >> 11;
    int i = tid & 2047;
    int Lb = i * 16;
    int row = Lb >> 8, c = (Lb & 255) ^ ((row & 7) << 4);
    const float4* p = reinterpret_cast<const float4*>(src + (size_t)layer * 16384 + row * 128 + (c >> 1));
    float4 a = p[0], b = p[1];
    short8 s;
    s[0]=f2bf(a.x); s[1]=f2bf(a.y); s[2]=f2bf(a.z); s[3]=f2bf(a.w);
    s[4]=f2bf(b.x); s[5]=f2bf(b.y); s[6]=f2bf(b.z); s[7]=f2bf(b.w);
    size_t off = ((size_t)layer * 3 + blockIdx.y) * 16384;
    *reinterpret_cast<short8*>(Wbf + off + (size_t)i * 8) = s;
}

// ---------------------------------------------------------------- fused QKV GEMM
// ONE launch: 512 blocks (XCD-grouped, matches attn's batch<->XCD map).
// X staged once; W (32KB, L2-hot) re-staged per mat between barriers.
// Outputs in FRAGMENT ORDER. Q pre-scaled by log2(e).
__global__ __launch_bounds__(256, 2) void k_qkv3(const short* __restrict__ X,
    const short* __restrict__ Wl,
    const float* __restrict__ bq, const float* __restrict__ bk, const float* __restrict__ bv,
    short* __restrict__ Qf, short* __restrict__ Kf, short* __restrict__ Vf) {
    __shared__ short xs[128 * 128];
    __shared__ short wsh[128 * 128];
    const int t = threadIdx.x;
    int flat = blockIdx.x, xcd = flat & 7, idx = flat >> 3;
    int rblk = xcd * 64 + idx;                 // XCD0 -> rows 0..8191 = batches 0..3
    const size_t rowbase = (size_t)rblk * 128;

    const char* Xg = reinterpret_cast<const char*>(X) + rowbase * 256;
#pragma unroll
    for (int p = 0; p < 8; p++) {
        int Lb = (p * 256 + t) * 16;
        int row = Lb >> 8, c = Lb & 255;
        gll16(Xg + (size_t)row * 256 + (c ^ ((row & 7) << 4)),
              reinterpret_cast<char*>(xs) + Lb);
    }
#pragma unroll
    for (int p = 0; p < 8; p++) {             // W for mat 0
        int Lb = (p * 256 + t) * 16;
        gll16(reinterpret_cast<const char*>(Wl) + Lb,
              reinterpret_cast<char*>(wsh) + Lb);
    }
    __syncthreads();

    const int wave = t >> 6, lane = t & 63, g = lane >> 4, ln = lane & 15;
    const int bb2 = (int)(rowbase >> 11);      // batch
    const int l0  = (int)(rowbase & (L_ - 1)); // row within batch

#pragma unroll
    for (int mat = 0; mat < 3; mat++) {
        if (mat > 0) {
            __syncthreads();                   // all waves done reading wsh (mat-1)
#pragma unroll
            for (int p = 0; p < 8; p++) {
                int Lb = (p * 256 + t) * 16;
                gll16(reinterpret_cast<const char*>(Wl + mat * 16384) + Lb,
                      reinterpret_cast<char*>(wsh) + Lb);
            }
            __syncthreads();                   // vmcnt(0) drained before barrier
        }
        const float* bias = (mat == 0) ? bq : (mat == 1) ? bk : bv;
        f32x4 acc[2][8];
#pragma unroll
        for (int mi = 0; mi < 2; mi++)
#pragma unroll
            for (int ni = 0; ni < 8; ni++) acc[mi][ni] = f32x4{0.f, 0.f, 0.f, 0.f};

        if (mat < 2) {
            // A = W (rows e), B = X (rows l) -> C[e][l]
#pragma unroll
            for (int kk = 0; kk < 4; kk++) {
                short8 aW[2];
#pragma unroll
                for (int mi = 0; mi < 2; mi++) {
                    int row = wave * 32 + mi * 16 + ln;
                    int byte = (row * 256 + kk * 64 + g * 16) ^ ((row & 7) << 4);
                    aW[mi] = *reinterpret_cast<const short8*>(reinterpret_cast<const char*>(wsh) + byte);
                }
#pragma unroll
                for (int ni = 0; ni < 8; ni++) {
                    int row = ni * 16 + ln;
                    int byte = (row * 256 + kk * 64 + g * 16) ^ ((row & 7) << 4);
                    short8 bX = *reinterpret_cast<const short8*>(reinterpret_cast<const char*>(xs) + byte);
                    acc[0][ni] = __builtin_amdgcn_mfma_f32_16x16x32_bf16(aW[0], bX, acc[0][ni], 0, 0, 0);
                    acc[1][ni] = __builtin_amdgcn_mfma_f32_16x16x32_bf16(aW[1], bX, acc[1][ni], 0, 0, 0);
                }
            }
            const float qscale = (mat == 0) ? 1.4426950408889634f : 1.0f;
            char* oc = reinterpret_cast<char*>((mat == 0) ? Qf : Kf) + ((size_t)bb2 << 19);
            int lidx_hi = ((g >> 1) & 1) << 5;
#pragma unroll
            for (int mi = 0; mi < 2; mi++) {
                int e0 = wave * 32 + mi * 16 + g * 4;
                int dst = wave * 2 + mi;
                float4 b4 = *reinterpret_cast<const float4*>(bias + e0);
#pragma unroll
                for (int ni = 0; ni < 8; ni++) {
                    unsigned lo = (unsigned short)f2bf((acc[mi][ni][0] + b4.x) * qscale)
                                | ((unsigned)(unsigned short)f2bf((acc[mi][ni][1] + b4.y) * qscale) << 16);
                    unsigned hi2 = (unsigned short)f2bf((acc[mi][ni][2] + b4.z) * qscale)
                                | ((unsigned)(unsigned short)f2bf((acc[mi][ni][3] + b4.w) * qscale) << 16);
                    int blk32 = (l0 >> 5) + (ni >> 1);
                    int l31 = ((ni & 1) << 4) + ln;
                    size_t off = ((size_t)(blk32 * 8 + dst) << 10)
                               + ((lidx_hi + l31) << 4) + ((g & 1) << 3);
                    int2 pk; pk.x = (int)lo; pk.y = (int)hi2;
                    *reinterpret_cast<int2*>(oc + off) = pk;
                }
            }
        } else {
            // V: A = X (rows l), B = W (rows e) -> C[l][e]
#pragma unroll
            for (int kk = 0; kk < 4; kk++) {
                short8 aX[2];
#pragma unroll
                for (int mi = 0; mi < 2; mi++) {
                    int row = wave * 32 + mi * 16 + ln;
                    int byte = (row * 256 + kk * 64 + g * 16) ^ ((row & 7) << 4);
                    aX[mi] = *reinterpret_cast<const short8*>(reinterpret_cast<const char*>(xs) + byte);
                }
#pragma unroll
                for (int ni = 0; ni < 8; ni++) {
                    int row = ni * 16 + ln;
                    int byte = (row * 256 + kk * 64 + g * 16) ^ ((row & 7) << 4);
                    short8 bW = *reinterpret_cast<const short8*>(reinterpret_cast<const char*>(wsh) + byte);
                    acc[0][ni] = __builtin_amdgcn_mfma_f32_16x16x32_bf16(aX[0], bW, acc[0][ni], 0, 0, 0);
                    acc[1][ni] = __builtin_amdgcn_mfma_f32_16x16x32_bf16(aX[1], bW, acc[1][ni], 0, 0, 0);
                }
            }
            char* oc = reinterpret_cast<char*>(Vf) + ((size_t)bb2 << 19);
#pragma unroll
            for (int ni = 0; ni < 8; ni++) {
                int d = ni * 16 + ln;
                float bvv = bias[d];
                int d2 = d >> 5, d31 = d & 31;
#pragma unroll
                for (int mi = 0; mi < 2; mi++) {
                    unsigned lo = (unsigned short)f2bf(acc[mi][ni][0] + bvv)
                                | ((unsigned)(unsigned short)f2bf(acc[mi][ni][1] + bvv) << 16);
                    unsigned hi2 = (unsigned short)f2bf(acc[mi][ni][2] + bvv)
                                | ((unsigned)(unsigned short)f2bf(acc[mi][ni][3] + bvv) << 16);
                    int lglob = l0 + wave * 32 + mi * 16 + g * 4;
                    int kt = lglob >> 6, k16 = (lglob >> 4) & 3, lhi = (lglob >> 3) & 1;
                    size_t off = ((size_t)kt << 14) + (k16 << 12) + (d2 << 10)
                               + ((lhi * 32 + d31) << 4) + ((g & 1) << 3);
                    int2 pk; pk.x = (int)lo; pk.y = (int)hi2;
                    *reinterpret_cast<int2*>(oc + off) = pk;
                }
            }
        }
    }
}

// ---------------------------------------------------------------- flash attention
// T15 pipeline: per iter QK(t) -> PV(t-1) [MFMA] || softmax(t) [VALU].
// V triple-buffered, K double-buffered. Deferred V wait: queue K-before-V,
// vmcnt(12) per iter -> V(t) stays in flight through the whole iteration.
__global__ __launch_bounds__(256, 2) void k_attn(const short* __restrict__ Qf,
                                                 const short* __restrict__ Kf,
                                                 const short* __restrict__ Vf,
                                                 short* __restrict__ Xo,
                                                 const float* __restrict__ rw,
                                                 const float* __restrict__ rb,
                                                 float* __restrict__ out,
                                                 int fuse) {
    __shared__ short Ks[2][KVB * 128];    // 2 x 16 KB, fragment order
    __shared__ short Vts[3][128 * KVB];   // 3 x 16 KB, fragment order
    const int t = threadIdx.x, w = t >> 6, lane = t & 63;
    const int hi = lane >> 5, c5 = lane & 31;
    int flat = blockIdx.x;
    int xcd = flat & 7, idx = flat >> 3;
    int b = xcd * 4 + (idx >> 4), qt = idx & 15;
    const size_t qbase = (size_t)b * L_ + qt * 128;

    // Q fragments -> registers (contiguous 1KB per load)
    const char* Qg = reinterpret_cast<const char*>(Qf) + ((size_t)b << 19);
    short8 qf[8];
#pragma unroll
    for (int dst = 0; dst < 8; dst++)
        qf[dst] = *reinterpret_cast<const short8*>(
            Qg + (((size_t)(qt * 4 + w) * 8 + dst) << 10) + lane * 16);
    __builtin_amdgcn_sched_barrier(0);    // pin Q loads before staging (vmcnt accounting)

    const char* Kg = reinterpret_cast<const char*>(Kf) + ((size_t)b << 19);
    const char* Vg = reinterpret_cast<const char*>(Vf) + ((size_t)b << 19);

    auto stageK = [&](int kt) {
#pragma unroll
        for (int p = 0; p < 4; p++) {
            int Lb = (p * 256 + t) * 16;
            gll16(Kg + ((size_t)kt << 14) + Lb, reinterpret_cast<char*>(Ks[kt & 1]) + Lb);
        }
    };
    auto stageV = [&](int kt) {
#pragma unroll
        for (int p = 0; p < 4; p++) {
            int Lb = (p * 256 + t) * 16;
            gll16(Vg + ((size_t)kt << 14) + Lb, reinterpret_cast<char*>(Vts[kt % 3]) + Lb);
        }
    };

    // issue queue: K0 K1 V0 V1 | K2 V2 | K3 V3 | ...  (K-before-V prefix property)
    stageK(0); stageK(1); stageV(0); stageV(1);

    f32x16 o[4];
#pragma unroll
    for (int d2 = 0; d2 < 4; d2++)
#pragma unroll
        for (int r = 0; r < 16; r++) o[d2][r] = 0.f;
    float lsum = 0.f;
    short8 pa[4];                         // P fragments of the PREVIOUS iter

    auto softmax = [&](const f32x16& s0, const f32x16& s1) {
        float e0[16], e1[16];
#pragma unroll
        for (int r = 0; r < 16; r++) { e0[r] = exp2g(s0[r]); e1[r] = exp2g(s1[r]); }
#pragma unroll
        for (int r = 0; r < 16; r++) lsum += e0[r] + e1[r];
#pragma unroll
        for (int kt16 = 0; kt16 < 4; kt16++) {
            const float* e = (kt16 < 2) ? e0 : e1;
            int rb2 = (kt16 & 1) * 8;
            unsigned w01 = cvtpk(e[rb2 + 0], e[rb2 + 1]);
            unsigned w23 = cvtpk(e[rb2 + 2], e[rb2 + 3]);
            unsigned w45 = cvtpk(e[rb2 + 4], e[rb2 + 5]);
            unsigned w67 = cvtpk(e[rb2 + 6], e[rb2 + 7]);
            plswap(w01, w45);
            plswap(w23, w67);
            uint4 fr; fr.x = w01; fr.y = w23; fr.z = w45; fr.w = w67;
            pa[kt16] = __builtin_bit_cast(short8, fr);
        }
    };
    auto qk = [&](int kt, f32x16& s0, f32x16& s1) {
        const char* Kb8 = reinterpret_cast<const char*>(Ks[kt & 1]) + lane * 16;
#pragma unroll
        for (int r = 0; r < 16; r++) { s0[r] = 0.f; s1[r] = 0.f; }
        __builtin_amdgcn_s_setprio(1);
#pragma unroll
        for (int dst = 0; dst < 8; dst++) {
            short8 kf0 = *reinterpret_cast<const short8*>(Kb8 + dst * 1024);
            short8 kf1 = *reinterpret_cast<const short8*>(Kb8 + 8192 + dst * 1024);
            s0 = __builtin_amdgcn_mfma_f32_32x32x16_bf16(kf0, qf[dst], s0, 0, 0, 0);
            s1 = __builtin_amdgcn_mfma_f32_32x32x16_bf16(kf1, qf[dst], s1, 0, 0, 0);
        }
        __builtin_amdgcn_s_setprio(0);
    };
    auto pv = [&](int kt) {               // O += P(kt).V(kt), pa holds P(kt)
        const char* Vb8 = reinterpret_cast<const char*>(Vts[kt % 3]) + lane * 16;
        __builtin_amdgcn_s_setprio(1);
#pragma unroll
        for (int kt16 = 0; kt16 < 4; kt16++) {
#pragma unroll
            for (int d2 = 0; d2 < 4; d2++) {
                short8 vf = *reinterpret_cast<const short8*>(Vb8 + kt16 * 4096 + d2 * 1024);
                o[d2] = __builtin_amdgcn_mfma_f32_32x32x16_bf16(pa[kt16], vf, o[d2], 0, 0, 0);
            }
        }
        __builtin_amdgcn_s_setprio(0);
    };

    // ---- peeled iter 0: QK(0) + softmax(0), no PV (needs only K0 landed)
    {
        asm volatile("s_waitcnt vmcnt(12)" ::: "memory");
        __builtin_amdgcn_sched_barrier(0);
        __builtin_amdgcn_s_barrier();
        f32x16 s0, s1;
        qk(0, s0, s1);
        softmax(s0, s1);
        __builtin_amdgcn_sched_barrier(0);
        __builtin_amdgcn_s_barrier();
        stageK(2); stageV(2);
    }
    // ---- main loop: QK(kt); PV(kt-1) || softmax(kt). Need K(kt), V(kt-1) landed.
    for (int kt = 1; kt < NKT; kt++) {
        if (kt < NKT - 1) asm volatile("s_waitcnt vmcnt(12)" ::: "memory");
        else              asm volatile("s_waitcnt vmcnt(0)" ::: "memory");
        __builtin_amdgcn_sched_barrier(0);
        __builtin_amdgcn_s_barrier();
        f32x16 s0, s1;
        qk(kt, s0, s1);
        pv(kt - 1);                        // MFMA, independent of s0/s1
        softmax(s0, s1);                   // VALU, scheduler interleaves into PV shadow
        __builtin_amdgcn_sched_barrier(0);
        __builtin_amdgcn_s_barrier();
        if (kt + 2 < NKT) { stageK(kt + 2); stageV(kt + 2); }
    }
    pv(NKT - 1);                           // final PV (all loads drained at last iter)

    // denominators
    lsum += __shfl_xor(lsum, 32, 64);

    if (!fuse) {
#pragma unroll
        for (int reg = 0; reg < 16; reg++) {
            int crow = (reg & 3) + 8 * (reg >> 2) + 4 * hi;
            float inv = 1.0f / __shfl(lsum, crow, 64);
            size_t rowg = qbase + w * 32 + crow;
#pragma unroll
            for (int d2 = 0; d2 < 4; d2++)
                Xo[rowg * D_ + d2 * 32 + c5] = f2bf(o[d2][reg] * inv);
        }
    } else {
        float part = 0.f;
#pragma unroll
        for (int reg = 0; reg < 16; reg++) {
            int crow = (reg & 3) + 8 * (reg >> 2) + 4 * hi;
            float inv = 1.0f / __shfl(lsum, crow, 64);
            size_t rowg = (size_t)(qt * 128 + w * 32 + crow) * D_;
#pragma unroll
            for (int d2 = 0; d2 < 4; d2++)
                part += (o[d2][reg] * inv) * rw[rowg + d2 * 32 + c5];
        }
#pragma unroll
        for (int off = 32; off > 0; off >>= 1) part += __shfl_xor(part, off, 64);
        if (lane == 0) atomicAdd(out + b, part);
        if (qt == 0 && t == 0) atomicAdd(out + b, rb[0]);
    }
}

// ---------------------------------------------------------------- launch
extern "C" void kernel_launch(void* const* d_in, const int* in_sizes, int n_in,
                              void* d_out, int out_size, void* d_ws, size_t ws_size,
                              hipStream_t stream) {
    const float* genotypes = (const float*)d_in[0];
    const float* emb       = (const float*)d_in[1];
    const float* qw        = (const float*)d_in[2];
    const float* qb        = (const float*)d_in[3];
    const float* kw        = (const float*)d_in[4];
    const float* kb        = (const float*)d_in[5];
    const float* vw        = (const float*)d_in[6];
    const float* vb        = (const float*)d_in[7];
    const float* rw        = (const float*)d_in[8];
    const float* rb        = (const float*)d_in[9];
    float* out = (float*)d_out;

    const size_t NBL = (size_t)B_ * L_;        // 65536
    short* X   = (short*)d_ws;
    short* Qf  = X  + NBL * D_;
    short* Kf  = Qf + NBL * D_;
    short* Vf  = Kf + NBL * D_;
    short* Wbf = Vf + NBL * D_;                // 3 layers x 3 mats x 16384 bf16 (pre-swizzled)

    hipMemsetAsync(out, 0, out_size * sizeof(float), stream);
    k_form_x<<<dim3((NBL * D_ / 8) / 256), 256, 0, stream>>>(genotypes, emb, X);
    k_convw<<<dim3(24, 3), 256, 0, stream>>>(qw, kw, vw, Wbf);
    for (int layer = 0; layer < NL_; layer++) {
        int boff = layer * D_;
        k_qkv3<<<dim3(512), 256, 0, stream>>>(X, Wbf + (size_t)layer * 3 * 16384,
                                              qb + boff, kb + boff, vb + boff,
                                              Qf, Kf, Vf);
        k_attn<<<dim3(512), 256, 0, stream>>>(Qf, Kf, Vf, X, rw, rb, out,
                                              layer == NL_ - 1 ? 1 : 0);
    }
}